// Round 5
// baseline (828.177 us; speedup 1.0000x reference)
//
#include <hip/hip_runtime.h>

#define V_NODES 50000
#define FDIM    512   // B*Cin
#define CIN     128
#define COUT    128
#define BATCH   4
#define KORD    5
#define KTOT    (KORD * CIN)   // 640

typedef short s16x8 __attribute__((ext_vector_type(8)));
typedef float f32x4 __attribute__((ext_vector_type(4)));

struct EPair { float w; int c; };   // interleaved edge: weight + col

__device__ __forceinline__ float bf2f(unsigned short u) {
    union { unsigned int i; float f; } x; x.i = ((unsigned int)u) << 16; return x.f;
}
__device__ __forceinline__ unsigned short f2bf(float f) {
    union { float f; unsigned int i; } x; x.f = f;
    unsigned int r = x.i + 0x7fffu + ((x.i >> 16) & 1u);   // RNE
    return (unsigned short)(r >> 16);
}

// ---------------- transpose: x (512, V) f32 -> T0 (V, 512) bf16 ------------
__global__ __launch_bounds__(256) void transpose_kernel(const float* __restrict__ x,
                                                        unsigned short* __restrict__ t0) {
    __shared__ float tile[64][65];
    const int v0 = blockIdx.x * 64;
    const int r0 = blockIdx.y * 64;
    const int lane = threadIdx.x & 63;
    const int w = threadIdx.x >> 6;
    #pragma unroll
    for (int i = 0; i < 16; ++i) {
        int rr = w * 16 + i;
        int v = v0 + lane;
        tile[rr][lane] = (v < V_NODES) ? x[(size_t)(r0 + rr) * V_NODES + v] : 0.0f;
    }
    __syncthreads();
    #pragma unroll
    for (int i = 0; i < 16; ++i) {
        int vv = w * 16 + i;
        int v = v0 + vv;
        if (v < V_NODES) t0[(size_t)v * FDIM + r0 + lane] = f2bf(tile[lane][vv]);
    }
}

// ---------------- W convert+transpose: W f32 [kci][co] -> WbT bf16 [co][kci]
__global__ __launch_bounds__(256) void convw_kernel(const float* __restrict__ W,
                                                    unsigned short* __restrict__ WbT) {
    int t = blockIdx.x * 256 + threadIdx.x;
    if (t >= KTOT * COUT) return;
    int kci = t >> 7, co = t & 127;
    WbT[(size_t)co * KTOT + kci] = f2bf(W[(size_t)kci * COUT + co]);
}

// ---------------- CSR build ------------------------------------------------
__global__ __launch_bounds__(256) void hist_kernel(const int* __restrict__ rows,
                                                   int* __restrict__ cnt, int E) {
    int e = blockIdx.x * 256 + threadIdx.x;
    if (e < E) atomicAdd(&cnt[rows[e]], 1);
}

__global__ __launch_bounds__(1024) void scan_kernel(const int* __restrict__ cnt,
                                                    int* __restrict__ rowPtr,
                                                    int* __restrict__ cursor) {
    __shared__ int partial[1024];
    const int T = 1024;
    const int chunk = (V_NODES + T - 1) / T;
    const int t = threadIdx.x;
    int lo = t * chunk, hi = min(lo + chunk, V_NODES);
    int s = 0;
    for (int i = lo; i < hi; ++i) s += cnt[i];
    partial[t] = s;
    __syncthreads();
    for (int off = 1; off < T; off <<= 1) {
        int v = (t >= off) ? partial[t - off] : 0;
        __syncthreads();
        partial[t] += v;
        __syncthreads();
    }
    int base = (t == 0) ? 0 : partial[t - 1];
    for (int i = lo; i < hi; ++i) {
        rowPtr[i] = base;
        cursor[i] = base;
        base += cnt[i];
    }
    if (t == T - 1) rowPtr[V_NODES] = base;
}

__global__ __launch_bounds__(256) void scatter_kernel(const float* __restrict__ vals,
                                                      const int* __restrict__ rows,
                                                      const int* __restrict__ cols,
                                                      int* __restrict__ cursor,
                                                      EPair* __restrict__ ep, int E) {
    int e = blockIdx.x * 256 + threadIdx.x;
    if (e >= E) return;
    int r = rows[e];
    int pos = atomicAdd(&cursor[r], 1);
    EPair p; p.w = vals[e]; p.c = cols[e];
    ep[pos] = p;
}

// ---------------- CSR SpMM bf16: y[row] = a*sum(w*x[col]) - beta*old[row] --
// persistent grid-stride waves; one wave per row; lane owns 8 bf16 (uint4).
// 8-deep edge unroll: 8 outstanding 1KB gathers per wave.
__global__ __launch_bounds__(256) void spmm_bf16_kernel(const EPair* __restrict__ ep,
                                                        const int* __restrict__ rowPtr,
                                                        const unsigned short* __restrict__ xsrc,
                                                        const unsigned short* __restrict__ xold,
                                                        unsigned short* __restrict__ y,
                                                        float alpha, int beta) {
    const int wid = threadIdx.x >> 6;
    const int lane = threadIdx.x & 63;
    const int wg0 = blockIdx.x * 4 + wid;
    const int nw = gridDim.x * 4;
    const uint4* __restrict__ xs = (const uint4*)xsrc;   // 64 uint4 per row

    for (int row = wg0; row < V_NODES; row += nw) {
        const int s = rowPtr[row], e_end = rowPtr[row + 1];

        float a0[8], a1[8];
        #pragma unroll
        for (int j = 0; j < 8; ++j) { a0[j] = 0.f; a1[j] = 0.f; }

        int e = s;
        for (; e + 7 < e_end; e += 8) {
            EPair p[8];
            #pragma unroll
            for (int i = 0; i < 8; ++i) p[i] = ep[e + i];
            uint4 q[8];
            #pragma unroll
            for (int i = 0; i < 8; ++i) q[i] = xs[(size_t)p[i].c * 64 + lane];
            #pragma unroll
            for (int i = 0; i < 8; ++i) {
                const float w = p[i].w;
                float* acc = (i & 1) ? a1 : a0;
                unsigned int uu[4] = {q[i].x, q[i].y, q[i].z, q[i].w};
                #pragma unroll
                for (int j = 0; j < 4; ++j) {
                    acc[2*j+0] += w * bf2f((unsigned short)(uu[j] & 0xffffu));
                    acc[2*j+1] += w * bf2f((unsigned short)(uu[j] >> 16));
                }
            }
        }
        for (; e + 1 < e_end; e += 2) {
            EPair p0 = ep[e], p1 = ep[e + 1];
            uint4 q0 = xs[(size_t)p0.c * 64 + lane];
            uint4 q1 = xs[(size_t)p1.c * 64 + lane];
            unsigned int u0[4] = {q0.x, q0.y, q0.z, q0.w};
            unsigned int u1[4] = {q1.x, q1.y, q1.z, q1.w};
            #pragma unroll
            for (int j = 0; j < 4; ++j) {
                a0[2*j+0] += p0.w * bf2f((unsigned short)(u0[j] & 0xffffu));
                a0[2*j+1] += p0.w * bf2f((unsigned short)(u0[j] >> 16));
                a1[2*j+0] += p1.w * bf2f((unsigned short)(u1[j] & 0xffffu));
                a1[2*j+1] += p1.w * bf2f((unsigned short)(u1[j] >> 16));
            }
        }
        if (e < e_end) {
            EPair p0 = ep[e];
            uint4 q0 = xs[(size_t)p0.c * 64 + lane];
            unsigned int u0[4] = {q0.x, q0.y, q0.z, q0.w};
            #pragma unroll
            for (int j = 0; j < 4; ++j) {
                a0[2*j+0] += p0.w * bf2f((unsigned short)(u0[j] & 0xffffu));
                a0[2*j+1] += p0.w * bf2f((unsigned short)(u0[j] >> 16));
            }
        }

        float r[8];
        #pragma unroll
        for (int j = 0; j < 8; ++j) r[j] = alpha * (a0[j] + a1[j]);
        if (beta) {
            uint4 q = ((const uint4*)xold)[(size_t)row * 64 + lane];
            unsigned int u[4] = {q.x, q.y, q.z, q.w};
            #pragma unroll
            for (int j = 0; j < 4; ++j) {
                r[2*j+0] -= bf2f((unsigned short)(u[j] & 0xffffu));
                r[2*j+1] -= bf2f((unsigned short)(u[j] >> 16));
            }
        }
        uint4 o;
        unsigned int* ou = (unsigned int*)&o;
        #pragma unroll
        for (int j = 0; j < 4; ++j)
            ou[j] = (unsigned int)f2bf(r[2*j]) | ((unsigned int)f2bf(r[2*j+1]) << 16);
        ((uint4*)y)[(size_t)row * 64 + lane] = o;
    }
}

// ---------------- fused MFMA GEMM over all K orders ------------------------
// out[b,co,v] = sum_{kci<640} T[kci>>7][v, b*128+(kci&127)] * WbT[co][kci] + bias[co]
// 128v x 128co tile, BK=64, double-buffered LDS A via global_load_lds (16B),
// XOR-swizzled (source-permute + read-permute, linear dest). B direct global.
__global__ __launch_bounds__(256) void gemm_mfma_kernel(const unsigned short* __restrict__ T,
                                                        const unsigned short* __restrict__ WbT,
                                                        const float* __restrict__ bias,
                                                        float* __restrict__ out) {
    __shared__ unsigned short Abuf[2][128 * 64];   // 2 x 16 KB
    const int lane = threadIdx.x & 63;
    const int wv = threadIdx.x >> 6;
    const int v0 = blockIdx.x * 128;
    const int b = blockIdx.y;
    const int lr = lane & 15;
    const int lk = lane >> 4;

    const int lanerow = lane >> 3;                 // 0..7 within 8-row slot
    const int cgp = (lane & 7) ^ lanerow;          // swizzled 16B col-group
    size_t goff[4];
    #pragma unroll
    for (int j = 0; j < 4; ++j) {
        int row_local = wv * 32 + j * 8 + lanerow;
        int rowg = v0 + row_local;
        if (rowg >= V_NODES) rowg = V_NODES - 1;   // clamp; rows masked at store
        goff[j] = (size_t)rowg * FDIM + b * CIN + cgp * 8;
    }

    f32x4 acc[8][2];
    #pragma unroll
    for (int mf = 0; mf < 8; ++mf)
        #pragma unroll
        for (int nf = 0; nf < 2; ++nf)
            acc[mf][nf] = (f32x4){0.f, 0.f, 0.f, 0.f};

    // prologue: stage step 0 into buf 0
    #pragma unroll
    for (int j = 0; j < 4; ++j)
        __builtin_amdgcn_global_load_lds(
            (const __attribute__((address_space(1))) void*)(T + goff[j]),
            (__attribute__((address_space(3))) void*)(&Abuf[0][(wv * 32 + j * 8) * 64]),
            16, 0, 0);
    __syncthreads();

    #pragma unroll 2
    for (int s = 0; s < 10; ++s) {     // 10 steps of BK=64 over KTOT=640
        const int cur = s & 1;
        if (s < 9) {
            const size_t stepoff = (size_t)((s + 1) >> 1) * V_NODES * FDIM + ((s + 1) & 1) * 64;
            #pragma unroll
            for (int j = 0; j < 4; ++j)
                __builtin_amdgcn_global_load_lds(
                    (const __attribute__((address_space(1))) void*)(T + goff[j] + stepoff),
                    (__attribute__((address_space(3))) void*)(&Abuf[cur ^ 1][(wv * 32 + j * 8) * 64]),
                    16, 0, 0);
        }
        const unsigned short* Ab = &Abuf[cur][0];
        #pragma unroll
        for (int c = 0; c < 2; ++c) {
            s16x8 bfr[2];
            #pragma unroll
            for (int nf = 0; nf < 2; ++nf)
                bfr[nf] = *(const s16x8*)(WbT + (size_t)(wv * 32 + nf * 16 + lr) * KTOT
                                          + s * 64 + c * 32 + lk * 8);
            s16x8 a[8];
            #pragma unroll
            for (int mf = 0; mf < 8; ++mf) {
                int rr = mf * 16 + lr;
                int slot = ((c * 4 + lk) ^ (lr & 7)) * 8;
                a[mf] = *(const s16x8*)(Ab + rr * 64 + slot);
            }
            #pragma unroll
            for (int mf = 0; mf < 8; ++mf)
                #pragma unroll
                for (int nf = 0; nf < 2; ++nf)
                    acc[mf][nf] = __builtin_amdgcn_mfma_f32_16x16x32_bf16(a[mf], bfr[nf], acc[mf][nf], 0, 0, 0);
        }
        __syncthreads();
    }

    // --- epilogue: transpose through LDS (reuse Abuf), coalesced stores ---
    float* lds_f = (float*)&Abuf[0][0];            // 32 co x 132 f32
    const float bs0 = bias[wv * 32 + lr];
    const float bs1 = bias[wv * 32 + 16 + lr];
    #pragma unroll
    for (int p = 0; p < 4; ++p) {
        if (wv == p) {
            #pragma unroll
            for (int mf = 0; mf < 8; ++mf)
                #pragma unroll
                for (int nf = 0; nf < 2; ++nf) {
                    int co_l = nf * 16 + lr;
                    int vbase = mf * 16 + lk * 4;
                    f32x4 val = acc[mf][nf];
                    float bs = nf ? bs1 : bs0;
                    val[0] += bs; val[1] += bs; val[2] += bs; val[3] += bs;
                    *(f32x4*)(lds_f + co_l * 132 + vbase) = val;
                }
        }
        __syncthreads();
        #pragma unroll
        for (int i = 0; i < 4; ++i) {
            int flat = i * 256 + threadIdx.x;
            int co_l = flat >> 5;
            int v4 = flat & 31;
            int v = v0 + v4 * 4;
            if (v < V_NODES) {
                f32x4 val = *(const f32x4*)(lds_f + co_l * 132 + v4 * 4);
                *(f32x4*)(out + (size_t)(b * COUT + p * 32 + co_l) * V_NODES + v) = val;
            }
        }
        __syncthreads();
    }
}

extern "C" void kernel_launch(void* const* d_in, const int* in_sizes, int n_in,
                              void* d_out, int out_size, void* d_ws, size_t ws_size,
                              hipStream_t stream) {
    const float* x    = (const float*)d_in[0];
    const float* vals = (const float*)d_in[1];
    const float* W    = (const float*)d_in[2];
    const float* bias = (const float*)d_in[3];
    const int* rows   = (const int*)d_in[4];
    const int* cols   = (const int*)d_in[5];
    const int E = in_sizes[1];
    float* out = (float*)d_out;

    // workspace: T0..T4 bf16 (each V*512), WbT bf16, edge pairs, CSR arrays
    unsigned short* T    = (unsigned short*)d_ws;
    unsigned short* WbT  = T + (size_t)KORD * V_NODES * FDIM;
    EPair* ep     = (EPair*)(WbT + (size_t)COUT * KTOT);
    int*   rowPtr = (int*)(ep + E);
    int*   cursor = rowPtr + V_NODES + 1;
    int*   cnt    = cursor + V_NODES;

    unsigned short* T0 = T;
    unsigned short* T1 = T + 1 * (size_t)V_NODES * FDIM;
    unsigned short* T2 = T + 2 * (size_t)V_NODES * FDIM;
    unsigned short* T3 = T + 3 * (size_t)V_NODES * FDIM;
    unsigned short* T4 = T + 4 * (size_t)V_NODES * FDIM;

    const int eBlocks = (E + 255) / 256;

    // CSR build
    hipMemsetAsync(cnt, 0, V_NODES * sizeof(int), stream);
    hist_kernel<<<eBlocks, 256, 0, stream>>>(rows, cnt, E);
    scan_kernel<<<1, 1024, 0, stream>>>(cnt, rowPtr, cursor);
    scatter_kernel<<<eBlocks, 256, 0, stream>>>(vals, rows, cols, cursor, ep, E);

    // T0 + weights
    dim3 tg((V_NODES + 63) / 64, FDIM / 64);
    transpose_kernel<<<tg, 256, 0, stream>>>(x, T0);
    convw_kernel<<<(KTOT * COUT + 255) / 256, 256, 0, stream>>>(W, WbT);

    // Chebyshev recurrence (all bf16), persistent SpMM
    const int spBlocks = 2048;
    spmm_bf16_kernel<<<spBlocks, 256, 0, stream>>>(ep, rowPtr, T0, T0, T1, 1.f, 0);
    spmm_bf16_kernel<<<spBlocks, 256, 0, stream>>>(ep, rowPtr, T1, T0, T2, 2.f, 1);
    spmm_bf16_kernel<<<spBlocks, 256, 0, stream>>>(ep, rowPtr, T2, T1, T3, 2.f, 1);
    spmm_bf16_kernel<<<spBlocks, 256, 0, stream>>>(ep, rowPtr, T3, T2, T4, 2.f, 1);

    // fused contraction over all 5 orders
    dim3 gg((V_NODES + 127) / 128, BATCH);
    gemm_mfma_kernel<<<gg, 256, 0, stream>>>(T, WbT, bias, out);
}

// Round 6
// 681.404 us; speedup vs baseline: 1.2154x; 1.2154x over previous
//
#include <hip/hip_runtime.h>

#define V_NODES 50000
#define FDIM    512   // B*Cin
#define CIN     128
#define COUT    128
#define BATCH   4
#define KORD    5
#define KTOT    (KORD * CIN)   // 640

typedef short s16x8 __attribute__((ext_vector_type(8)));
typedef float f32x4 __attribute__((ext_vector_type(4)));

struct EPair { float w; int c; };   // interleaved edge: weight + col

__device__ __forceinline__ float bf2f(unsigned short u) {
    union { unsigned int i; float f; } x; x.i = ((unsigned int)u) << 16; return x.f;
}
__device__ __forceinline__ unsigned short f2bf(float f) {
    union { float f; unsigned int i; } x; x.f = f;
    unsigned int r = x.i + 0x7fffu + ((x.i >> 16) & 1u);   // RNE
    return (unsigned short)(r >> 16);
}

// ---------------- transpose: x (512, V) f32 -> T0 (V, 512) bf16 ------------
__global__ __launch_bounds__(256) void transpose_kernel(const float* __restrict__ x,
                                                        unsigned short* __restrict__ t0) {
    __shared__ float tile[64][65];
    const int v0 = blockIdx.x * 64;
    const int r0 = blockIdx.y * 64;
    const int lane = threadIdx.x & 63;
    const int w = threadIdx.x >> 6;
    #pragma unroll
    for (int i = 0; i < 16; ++i) {
        int rr = w * 16 + i;
        int v = v0 + lane;
        tile[rr][lane] = (v < V_NODES) ? x[(size_t)(r0 + rr) * V_NODES + v] : 0.0f;
    }
    __syncthreads();
    #pragma unroll
    for (int i = 0; i < 16; ++i) {
        int vv = w * 16 + i;
        int v = v0 + vv;
        if (v < V_NODES) t0[(size_t)v * FDIM + r0 + lane] = f2bf(tile[lane][vv]);
    }
}

// ---------------- W convert+transpose: W f32 [kci][co] -> WbT bf16 [co][kci]
__global__ __launch_bounds__(256) void convw_kernel(const float* __restrict__ W,
                                                    unsigned short* __restrict__ WbT) {
    int t = blockIdx.x * 256 + threadIdx.x;
    if (t >= KTOT * COUT) return;
    int kci = t >> 7, co = t & 127;
    WbT[(size_t)co * KTOT + kci] = f2bf(W[(size_t)kci * COUT + co]);
}

// ---------------- CSR build ------------------------------------------------
__global__ __launch_bounds__(256) void hist_kernel(const int* __restrict__ rows,
                                                   int* __restrict__ cnt, int E) {
    int e = blockIdx.x * 256 + threadIdx.x;
    if (e < E) atomicAdd(&cnt[rows[e]], 1);
}

__global__ __launch_bounds__(1024) void scan_kernel(const int* __restrict__ cnt,
                                                    int* __restrict__ rowPtr,
                                                    int* __restrict__ cursor) {
    __shared__ int partial[1024];
    const int T = 1024;
    const int chunk = (V_NODES + T - 1) / T;
    const int t = threadIdx.x;
    int lo = t * chunk, hi = min(lo + chunk, V_NODES);
    int s = 0;
    for (int i = lo; i < hi; ++i) s += cnt[i];
    partial[t] = s;
    __syncthreads();
    for (int off = 1; off < T; off <<= 1) {
        int v = (t >= off) ? partial[t - off] : 0;
        __syncthreads();
        partial[t] += v;
        __syncthreads();
    }
    int base = (t == 0) ? 0 : partial[t - 1];
    for (int i = lo; i < hi; ++i) {
        rowPtr[i] = base;
        cursor[i] = base;
        base += cnt[i];
    }
    if (t == T - 1) rowPtr[V_NODES] = base;
}

__global__ __launch_bounds__(256) void scatter_kernel(const float* __restrict__ vals,
                                                      const int* __restrict__ rows,
                                                      const int* __restrict__ cols,
                                                      int* __restrict__ cursor,
                                                      EPair* __restrict__ ep, int E) {
    int e = blockIdx.x * 256 + threadIdx.x;
    if (e >= E) return;
    int r = rows[e];
    int pos = atomicAdd(&cursor[r], 1);
    EPair p; p.w = vals[e]; p.c = cols[e];
    ep[pos] = p;
}

// ---------------- quantize bf16 rows -> int8 + per-row scale ---------------
__global__ __launch_bounds__(256) void quant_rows_kernel(const unsigned short* __restrict__ xb,
                                                         signed char* __restrict__ xi,
                                                         float* __restrict__ xs) {
    const int wid = threadIdx.x >> 6;
    const int lane = threadIdx.x & 63;
    const int row = blockIdx.x * 4 + wid;
    if (row >= V_NODES) return;
    uint4 q = ((const uint4*)xb)[(size_t)row * 64 + lane];
    unsigned int u[4] = {q.x, q.y, q.z, q.w};
    float f[8];
    #pragma unroll
    for (int j = 0; j < 4; ++j) {
        f[2*j+0] = bf2f((unsigned short)(u[j] & 0xffffu));
        f[2*j+1] = bf2f((unsigned short)(u[j] >> 16));
    }
    float m = 0.f;
    #pragma unroll
    for (int j = 0; j < 8; ++j) m = fmaxf(m, fabsf(f[j]));
    #pragma unroll
    for (int off = 1; off < 64; off <<= 1) m = fmaxf(m, __shfl_xor(m, off, 64));
    float inv = (m > 0.f) ? 127.f / m : 0.f;
    uint2 o; unsigned int ow[2] = {0u, 0u};
    #pragma unroll
    for (int j = 0; j < 8; ++j) {
        int si = (int)rintf(f[j] * inv);
        si = max(-127, min(127, si));
        ow[j >> 2] |= ((unsigned int)(si & 0xff)) << (8 * (j & 3));
    }
    o.x = ow[0]; o.y = ow[1];
    ((uint2*)xi)[(size_t)row * 64 + lane] = o;
    if (lane == 0) xs[row] = m / 127.f;
}

// ---------------- CSR SpMM from int8 source --------------------------------
// y[row] = alpha * sum(w * scale[c] * xi8[c]) - beta*old[row]; writes bf16 y
// and (optionally) its own int8+scale copy for the next pass.
__global__ __launch_bounds__(256) void spmm_i8_kernel(const EPair* __restrict__ ep,
                                                      const int* __restrict__ rowPtr,
                                                      const signed char* __restrict__ xi,
                                                      const float* __restrict__ xsc,
                                                      const unsigned short* __restrict__ xold,
                                                      unsigned short* __restrict__ y,
                                                      signed char* __restrict__ yi,
                                                      float* __restrict__ ysc,
                                                      float alpha, int beta, int wri8) {
    const int wid = threadIdx.x >> 6;
    const int lane = threadIdx.x & 63;
    const int row = blockIdx.x * 4 + wid;
    if (row >= V_NODES) return;
    const int s = rowPtr[row], e_end = rowPtr[row + 1];
    const uint2* __restrict__ xq = (const uint2*)xi;   // 64 x 8B per row

    float acc[8];
    #pragma unroll
    for (int j = 0; j < 8; ++j) acc[j] = 0.f;

    int e = s;
    for (; e + 3 < e_end; e += 4) {
        EPair p[4];
        #pragma unroll
        for (int i = 0; i < 4; ++i) p[i] = ep[e + i];
        float w[4];
        #pragma unroll
        for (int i = 0; i < 4; ++i) w[i] = p[i].w * xsc[p[i].c];
        uint2 q[4];
        #pragma unroll
        for (int i = 0; i < 4; ++i) q[i] = xq[(size_t)p[i].c * 64 + lane];
        #pragma unroll
        for (int i = 0; i < 4; ++i) {
            #pragma unroll
            for (int wd = 0; wd < 2; ++wd) {
                unsigned int uu = wd ? q[i].y : q[i].x;
                #pragma unroll
                for (int b = 0; b < 4; ++b) {
                    float xv = (float)((signed char)(uu >> (8 * b)));
                    acc[wd * 4 + b] += w[i] * xv;
                }
            }
        }
    }
    for (; e < e_end; ++e) {
        EPair p0 = ep[e];
        float w0 = p0.w * xsc[p0.c];
        uint2 q0 = xq[(size_t)p0.c * 64 + lane];
        #pragma unroll
        for (int wd = 0; wd < 2; ++wd) {
            unsigned int uu = wd ? q0.y : q0.x;
            #pragma unroll
            for (int b = 0; b < 4; ++b) {
                float xv = (float)((signed char)(uu >> (8 * b)));
                acc[wd * 4 + b] += w0 * xv;
            }
        }
    }

    float r[8];
    #pragma unroll
    for (int j = 0; j < 8; ++j) r[j] = alpha * acc[j];
    if (beta) {
        uint4 q = ((const uint4*)xold)[(size_t)row * 64 + lane];
        unsigned int u[4] = {q.x, q.y, q.z, q.w};
        #pragma unroll
        for (int j = 0; j < 4; ++j) {
            r[2*j+0] -= bf2f((unsigned short)(u[j] & 0xffffu));
            r[2*j+1] -= bf2f((unsigned short)(u[j] >> 16));
        }
    }
    uint4 o;
    unsigned int* ou = (unsigned int*)&o;
    #pragma unroll
    for (int j = 0; j < 4; ++j)
        ou[j] = (unsigned int)f2bf(r[2*j]) | ((unsigned int)f2bf(r[2*j+1]) << 16);
    ((uint4*)y)[(size_t)row * 64 + lane] = o;

    if (wri8) {
        float m = 0.f;
        #pragma unroll
        for (int j = 0; j < 8; ++j) m = fmaxf(m, fabsf(r[j]));
        #pragma unroll
        for (int off = 1; off < 64; off <<= 1) m = fmaxf(m, __shfl_xor(m, off, 64));
        float inv = (m > 0.f) ? 127.f / m : 0.f;
        unsigned int ow[2] = {0u, 0u};
        #pragma unroll
        for (int j = 0; j < 8; ++j) {
            int si = (int)rintf(r[j] * inv);
            si = max(-127, min(127, si));
            ow[j >> 2] |= ((unsigned int)(si & 0xff)) << (8 * (j & 3));
        }
        uint2 oi; oi.x = ow[0]; oi.y = ow[1];
        ((uint2*)yi)[(size_t)row * 64 + lane] = oi;
        if (lane == 0) ysc[row] = m / 127.f;
    }
}

// ---------------- bf16-gather SpMM (fallback when ws too small) ------------
__global__ __launch_bounds__(256) void spmm_bf16_kernel(const EPair* __restrict__ ep,
                                                        const int* __restrict__ rowPtr,
                                                        const unsigned short* __restrict__ xsrc,
                                                        const unsigned short* __restrict__ xold,
                                                        unsigned short* __restrict__ y,
                                                        float alpha, int beta) {
    const int wid = threadIdx.x >> 6;
    const int lane = threadIdx.x & 63;
    const int row = blockIdx.x * 4 + wid;
    if (row >= V_NODES) return;
    const int s = rowPtr[row], e_end = rowPtr[row + 1];
    const uint4* __restrict__ xs = (const uint4*)xsrc;

    float a0[8], a1[8];
    #pragma unroll
    for (int j = 0; j < 8; ++j) { a0[j] = 0.f; a1[j] = 0.f; }

    int e = s;
    for (; e + 3 < e_end; e += 4) {
        EPair p0 = ep[e], p1 = ep[e+1], p2 = ep[e+2], p3 = ep[e+3];
        uint4 q0 = xs[(size_t)p0.c * 64 + lane];
        uint4 q1 = xs[(size_t)p1.c * 64 + lane];
        uint4 q2 = xs[(size_t)p2.c * 64 + lane];
        uint4 q3 = xs[(size_t)p3.c * 64 + lane];
        unsigned int u0[4] = {q0.x, q0.y, q0.z, q0.w};
        unsigned int u1[4] = {q1.x, q1.y, q1.z, q1.w};
        unsigned int u2[4] = {q2.x, q2.y, q2.z, q2.w};
        unsigned int u3[4] = {q3.x, q3.y, q3.z, q3.w};
        #pragma unroll
        for (int j = 0; j < 4; ++j) {
            a0[2*j+0] += p0.w * bf2f((unsigned short)(u0[j] & 0xffffu));
            a0[2*j+1] += p0.w * bf2f((unsigned short)(u0[j] >> 16));
            a1[2*j+0] += p1.w * bf2f((unsigned short)(u1[j] & 0xffffu));
            a1[2*j+1] += p1.w * bf2f((unsigned short)(u1[j] >> 16));
            a0[2*j+0] += p2.w * bf2f((unsigned short)(u2[j] & 0xffffu));
            a0[2*j+1] += p2.w * bf2f((unsigned short)(u2[j] >> 16));
            a1[2*j+0] += p3.w * bf2f((unsigned short)(u3[j] & 0xffffu));
            a1[2*j+1] += p3.w * bf2f((unsigned short)(u3[j] >> 16));
        }
    }
    for (; e < e_end; ++e) {
        EPair p0 = ep[e];
        uint4 q0 = xs[(size_t)p0.c * 64 + lane];
        unsigned int u0[4] = {q0.x, q0.y, q0.z, q0.w};
        #pragma unroll
        for (int j = 0; j < 4; ++j) {
            a0[2*j+0] += p0.w * bf2f((unsigned short)(u0[j] & 0xffffu));
            a0[2*j+1] += p0.w * bf2f((unsigned short)(u0[j] >> 16));
        }
    }

    float r[8];
    #pragma unroll
    for (int j = 0; j < 8; ++j) r[j] = alpha * (a0[j] + a1[j]);
    if (beta) {
        uint4 q = ((const uint4*)xold)[(size_t)row * 64 + lane];
        unsigned int u[4] = {q.x, q.y, q.z, q.w};
        #pragma unroll
        for (int j = 0; j < 4; ++j) {
            r[2*j+0] -= bf2f((unsigned short)(u[j] & 0xffffu));
            r[2*j+1] -= bf2f((unsigned short)(u[j] >> 16));
        }
    }
    uint4 o;
    unsigned int* ou = (unsigned int*)&o;
    #pragma unroll
    for (int j = 0; j < 4; ++j)
        ou[j] = (unsigned int)f2bf(r[2*j]) | ((unsigned int)f2bf(r[2*j+1]) << 16);
    ((uint4*)y)[(size_t)row * 64 + lane] = o;
}

// ---------------- fused MFMA GEMM over all K orders ------------------------
__global__ __launch_bounds__(256) void gemm_mfma_kernel(const unsigned short* __restrict__ T,
                                                        const unsigned short* __restrict__ WbT,
                                                        const float* __restrict__ bias,
                                                        float* __restrict__ out) {
    __shared__ unsigned short Abuf[2][128 * 64];   // 2 x 16 KB
    const int lane = threadIdx.x & 63;
    const int wv = threadIdx.x >> 6;
    const int v0 = blockIdx.x * 128;
    const int b = blockIdx.y;
    const int lr = lane & 15;
    const int lk = lane >> 4;

    const int lanerow = lane >> 3;
    const int cgp = (lane & 7) ^ lanerow;
    size_t goff[4];
    #pragma unroll
    for (int j = 0; j < 4; ++j) {
        int row_local = wv * 32 + j * 8 + lanerow;
        int rowg = v0 + row_local;
        if (rowg >= V_NODES) rowg = V_NODES - 1;
        goff[j] = (size_t)rowg * FDIM + b * CIN + cgp * 8;
    }

    f32x4 acc[8][2];
    #pragma unroll
    for (int mf = 0; mf < 8; ++mf)
        #pragma unroll
        for (int nf = 0; nf < 2; ++nf)
            acc[mf][nf] = (f32x4){0.f, 0.f, 0.f, 0.f};

    #pragma unroll
    for (int j = 0; j < 4; ++j)
        __builtin_amdgcn_global_load_lds(
            (const __attribute__((address_space(1))) void*)(T + goff[j]),
            (__attribute__((address_space(3))) void*)(&Abuf[0][(wv * 32 + j * 8) * 64]),
            16, 0, 0);
    __syncthreads();

    #pragma unroll 2
    for (int s = 0; s < 10; ++s) {
        const int cur = s & 1;
        if (s < 9) {
            const size_t stepoff = (size_t)((s + 1) >> 1) * V_NODES * FDIM + ((s + 1) & 1) * 64;
            #pragma unroll
            for (int j = 0; j < 4; ++j)
                __builtin_amdgcn_global_load_lds(
                    (const __attribute__((address_space(1))) void*)(T + goff[j] + stepoff),
                    (__attribute__((address_space(3))) void*)(&Abuf[cur ^ 1][(wv * 32 + j * 8) * 64]),
                    16, 0, 0);
        }
        const unsigned short* Ab = &Abuf[cur][0];
        #pragma unroll
        for (int c = 0; c < 2; ++c) {
            s16x8 bfr[2];
            #pragma unroll
            for (int nf = 0; nf < 2; ++nf)
                bfr[nf] = *(const s16x8*)(WbT + (size_t)(wv * 32 + nf * 16 + lr) * KTOT
                                          + s * 64 + c * 32 + lk * 8);
            s16x8 a[8];
            #pragma unroll
            for (int mf = 0; mf < 8; ++mf) {
                int rr = mf * 16 + lr;
                int slot = ((c * 4 + lk) ^ (lr & 7)) * 8;
                a[mf] = *(const s16x8*)(Ab + rr * 64 + slot);
            }
            #pragma unroll
            for (int mf = 0; mf < 8; ++mf)
                #pragma unroll
                for (int nf = 0; nf < 2; ++nf)
                    acc[mf][nf] = __builtin_amdgcn_mfma_f32_16x16x32_bf16(a[mf], bfr[nf], acc[mf][nf], 0, 0, 0);
        }
        __syncthreads();
    }

    float* lds_f = (float*)&Abuf[0][0];
    const float bs0 = bias[wv * 32 + lr];
    const float bs1 = bias[wv * 32 + 16 + lr];
    #pragma unroll
    for (int p = 0; p < 4; ++p) {
        if (wv == p) {
            #pragma unroll
            for (int mf = 0; mf < 8; ++mf)
                #pragma unroll
                for (int nf = 0; nf < 2; ++nf) {
                    int co_l = nf * 16 + lr;
                    int vbase = mf * 16 + lk * 4;
                    f32x4 val = acc[mf][nf];
                    float bs = nf ? bs1 : bs0;
                    val[0] += bs; val[1] += bs; val[2] += bs; val[3] += bs;
                    *(f32x4*)(lds_f + co_l * 132 + vbase) = val;
                }
        }
        __syncthreads();
        #pragma unroll
        for (int i = 0; i < 4; ++i) {
            int flat = i * 256 + threadIdx.x;
            int co_l = flat >> 5;
            int v4 = flat & 31;
            int v = v0 + v4 * 4;
            if (v < V_NODES) {
                f32x4 val = *(const f32x4*)(lds_f + co_l * 132 + v4 * 4);
                *(f32x4*)(out + (size_t)(b * COUT + p * 32 + co_l) * V_NODES + v) = val;
            }
        }
        __syncthreads();
    }
}

extern "C" void kernel_launch(void* const* d_in, const int* in_sizes, int n_in,
                              void* d_out, int out_size, void* d_ws, size_t ws_size,
                              hipStream_t stream) {
    const float* x    = (const float*)d_in[0];
    const float* vals = (const float*)d_in[1];
    const float* W    = (const float*)d_in[2];
    const float* bias = (const float*)d_in[3];
    const int* rows   = (const int*)d_in[4];
    const int* cols   = (const int*)d_in[5];
    const int E = in_sizes[1];
    float* out = (float*)d_out;

    // base workspace layout
    unsigned short* T    = (unsigned short*)d_ws;
    unsigned short* WbT  = T + (size_t)KORD * V_NODES * FDIM;
    EPair* ep     = (EPair*)(WbT + (size_t)COUT * KTOT);
    int*   rowPtr = (int*)(ep + E);
    int*   cursor = rowPtr + V_NODES + 1;
    int*   cnt    = cursor + V_NODES;
    // optional int8 region (aligned 16)
    char* p8 = (char*)(((uintptr_t)(cnt + V_NODES) + 15) & ~(uintptr_t)15);
    signed char* i8A = (signed char*)p8;
    signed char* i8B = i8A + (size_t)V_NODES * FDIM;
    float* scA = (float*)(i8B + (size_t)V_NODES * FDIM);
    float* scB = scA + V_NODES;
    size_t need = (size_t)((char*)(scB + V_NODES) - (char*)d_ws);
    const bool use_i8 = (ws_size >= need);

    unsigned short* T0 = T;
    unsigned short* T1 = T + 1 * (size_t)V_NODES * FDIM;
    unsigned short* T2 = T + 2 * (size_t)V_NODES * FDIM;
    unsigned short* T3 = T + 3 * (size_t)V_NODES * FDIM;
    unsigned short* T4 = T + 4 * (size_t)V_NODES * FDIM;

    const int eBlocks = (E + 255) / 256;
    const int spB4 = (V_NODES + 3) / 4;

    // CSR build
    hipMemsetAsync(cnt, 0, V_NODES * sizeof(int), stream);
    hist_kernel<<<eBlocks, 256, 0, stream>>>(rows, cnt, E);
    scan_kernel<<<1, 1024, 0, stream>>>(cnt, rowPtr, cursor);
    scatter_kernel<<<eBlocks, 256, 0, stream>>>(vals, rows, cols, cursor, ep, E);

    // T0 + weights
    dim3 tg((V_NODES + 63) / 64, FDIM / 64);
    transpose_kernel<<<tg, 256, 0, stream>>>(x, T0);
    convw_kernel<<<(KTOT * COUT + 255) / 256, 256, 0, stream>>>(W, WbT);

    if (use_i8) {
        quant_rows_kernel<<<spB4, 256, 0, stream>>>(T0, i8A, scA);
        spmm_i8_kernel<<<spB4, 256, 0, stream>>>(ep, rowPtr, i8A, scA, T0, T1, i8B, scB, 1.f, 0, 1);
        spmm_i8_kernel<<<spB4, 256, 0, stream>>>(ep, rowPtr, i8B, scB, T0, T2, i8A, scA, 2.f, 1, 1);
        spmm_i8_kernel<<<spB4, 256, 0, stream>>>(ep, rowPtr, i8A, scA, T1, T3, i8B, scB, 2.f, 1, 1);
        spmm_i8_kernel<<<spB4, 256, 0, stream>>>(ep, rowPtr, i8B, scB, T2, T4, i8A, scA, 2.f, 1, 0);
    } else {
        spmm_bf16_kernel<<<spB4, 256, 0, stream>>>(ep, rowPtr, T0, T0, T1, 1.f, 0);
        spmm_bf16_kernel<<<spB4, 256, 0, stream>>>(ep, rowPtr, T1, T0, T2, 2.f, 1);
        spmm_bf16_kernel<<<spB4, 256, 0, stream>>>(ep, rowPtr, T2, T1, T3, 2.f, 1);
        spmm_bf16_kernel<<<spB4, 256, 0, stream>>>(ep, rowPtr, T3, T2, T4, 2.f, 1);
    }

    // fused contraction over all 5 orders
    dim3 gg((V_NODES + 127) / 128, BATCH);
    gemm_mfma_kernel<<<gg, 256, 0, stream>>>(T, WbT, bias, out);
}

// Round 7
// 580.672 us; speedup vs baseline: 1.4262x; 1.1735x over previous
//
#include <hip/hip_runtime.h>

#define V_NODES 50000
#define FDIM    512   // B*Cin
#define CIN     128
#define COUT    128
#define BATCH   4
#define KORD    5
#define KTOT    (KORD * CIN)   // 640
#define SCAN_NBLK ((V_NODES + 255) / 256)   // 196

typedef short s16x8 __attribute__((ext_vector_type(8)));
typedef float f32x4 __attribute__((ext_vector_type(4)));

struct EPair { float w; int c; };   // interleaved edge: weight + col

__device__ __forceinline__ float bf2f(unsigned short u) {
    union { unsigned int i; float f; } x; x.i = ((unsigned int)u) << 16; return x.f;
}
__device__ __forceinline__ unsigned short f2bf(float f) {
    union { float f; unsigned int i; } x; x.f = f;
    unsigned int r = x.i + 0x7fffu + ((x.i >> 16) & 1u);   // RNE
    return (unsigned short)(r >> 16);
}

// ---------------- transpose: x (512, V) f32 -> T0 (V, 512) bf16 ------------
__global__ __launch_bounds__(256) void transpose_kernel(const float* __restrict__ x,
                                                        unsigned short* __restrict__ t0) {
    __shared__ float tile[64][65];
    const int v0 = blockIdx.x * 64;
    const int r0 = blockIdx.y * 64;
    const int lane = threadIdx.x & 63;
    const int w = threadIdx.x >> 6;
    #pragma unroll
    for (int i = 0; i < 16; ++i) {
        int rr = w * 16 + i;
        int v = v0 + lane;
        tile[rr][lane] = (v < V_NODES) ? x[(size_t)(r0 + rr) * V_NODES + v] : 0.0f;
    }
    __syncthreads();
    #pragma unroll
    for (int i = 0; i < 16; ++i) {
        int vv = w * 16 + i;
        int v = v0 + vv;
        if (v < V_NODES) t0[(size_t)v * FDIM + r0 + lane] = f2bf(tile[lane][vv]);
    }
}

// ---------------- W convert+transpose: W f32 [kci][co] -> WbT bf16 [co][kci]
__global__ __launch_bounds__(256) void convw_kernel(const float* __restrict__ W,
                                                    unsigned short* __restrict__ WbT) {
    int t = blockIdx.x * 256 + threadIdx.x;
    if (t >= KTOT * COUT) return;
    int kci = t >> 7, co = t & 127;
    WbT[(size_t)co * KTOT + kci] = f2bf(W[(size_t)kci * COUT + co]);
}

// ---------------- CSR build ------------------------------------------------
__global__ __launch_bounds__(256) void hist_kernel(const int* __restrict__ rows,
                                                   int* __restrict__ cnt, int E) {
    int e = blockIdx.x * 256 + threadIdx.x;
    if (e < E) atomicAdd(&cnt[rows[e]], 1);
}

// hierarchical scan, phase 1: per-block exclusive scan + block sums
__global__ __launch_bounds__(256) void scan1_kernel(const int* __restrict__ cnt,
                                                    int* __restrict__ rowPtr,
                                                    int* __restrict__ blkSum) {
    __shared__ int sh[256];
    const int t = threadIdx.x;
    const int i = blockIdx.x * 256 + t;
    int v = (i < V_NODES) ? cnt[i] : 0;
    sh[t] = v;
    __syncthreads();
    #pragma unroll
    for (int off = 1; off < 256; off <<= 1) {
        int u = (t >= off) ? sh[t - off] : 0;
        __syncthreads();
        sh[t] += u;
        __syncthreads();
    }
    if (i < V_NODES) rowPtr[i] = sh[t] - v;      // block-local exclusive
    if (t == 255) blkSum[blockIdx.x] = sh[255];
}

// phase 2: scan block sums (SCAN_NBLK <= 256), write grand total to rowPtr[V]
__global__ __launch_bounds__(256) void scan2_kernel(const int* __restrict__ blkSum,
                                                    int* __restrict__ blkOff,
                                                    int* __restrict__ rowPtr) {
    __shared__ int sh[256];
    const int t = threadIdx.x;
    int v = (t < SCAN_NBLK) ? blkSum[t] : 0;
    sh[t] = v;
    __syncthreads();
    #pragma unroll
    for (int off = 1; off < 256; off <<= 1) {
        int u = (t >= off) ? sh[t - off] : 0;
        __syncthreads();
        sh[t] += u;
        __syncthreads();
    }
    if (t < SCAN_NBLK) blkOff[t] = sh[t] - v;    // exclusive
    if (t == 255) rowPtr[V_NODES] = sh[255];
}

// phase 3: add block offsets; produce final rowPtr and cursor
__global__ __launch_bounds__(256) void scan3_kernel(int* __restrict__ rowPtr,
                                                    const int* __restrict__ blkOff,
                                                    int* __restrict__ cursor) {
    const int i = blockIdx.x * 256 + threadIdx.x;
    if (i >= V_NODES) return;
    int r = rowPtr[i] + blkOff[blockIdx.x];
    rowPtr[i] = r;
    cursor[i] = r;
}

__global__ __launch_bounds__(256) void scatter_kernel(const float* __restrict__ vals,
                                                      const int* __restrict__ rows,
                                                      const int* __restrict__ cols,
                                                      int* __restrict__ cursor,
                                                      EPair* __restrict__ ep, int E) {
    int e = blockIdx.x * 256 + threadIdx.x;
    if (e >= E) return;
    int r = rows[e];
    int pos = atomicAdd(&cursor[r], 1);
    EPair p; p.w = vals[e]; p.c = cols[e];
    ep[pos] = p;
}

// ---------------- quantize bf16 rows -> int8 + per-row scale ---------------
__global__ __launch_bounds__(256) void quant_rows_kernel(const unsigned short* __restrict__ xb,
                                                         signed char* __restrict__ xi,
                                                         float* __restrict__ xs) {
    const int wid = threadIdx.x >> 6;
    const int lane = threadIdx.x & 63;
    const int row = blockIdx.x * 4 + wid;
    if (row >= V_NODES) return;
    uint4 q = ((const uint4*)xb)[(size_t)row * 64 + lane];
    unsigned int u[4] = {q.x, q.y, q.z, q.w};
    float f[8];
    #pragma unroll
    for (int j = 0; j < 4; ++j) {
        f[2*j+0] = bf2f((unsigned short)(u[j] & 0xffffu));
        f[2*j+1] = bf2f((unsigned short)(u[j] >> 16));
    }
    float m = 0.f;
    #pragma unroll
    for (int j = 0; j < 8; ++j) m = fmaxf(m, fabsf(f[j]));
    #pragma unroll
    for (int off = 1; off < 64; off <<= 1) m = fmaxf(m, __shfl_xor(m, off, 64));
    float inv = (m > 0.f) ? 127.f / m : 0.f;
    uint2 o; unsigned int ow[2] = {0u, 0u};
    #pragma unroll
    for (int j = 0; j < 8; ++j) {
        int si = (int)rintf(f[j] * inv);
        si = max(-127, min(127, si));
        ow[j >> 2] |= ((unsigned int)(si & 0xff)) << (8 * (j & 3));
    }
    o.x = ow[0]; o.y = ow[1];
    ((uint2*)xi)[(size_t)row * 64 + lane] = o;
    if (lane == 0) xs[row] = m / 127.f;
}

// ---------------- CSR SpMM from int8 source --------------------------------
__global__ __launch_bounds__(256) void spmm_i8_kernel(const EPair* __restrict__ ep,
                                                      const int* __restrict__ rowPtr,
                                                      const signed char* __restrict__ xi,
                                                      const float* __restrict__ xsc,
                                                      const unsigned short* __restrict__ xold,
                                                      unsigned short* __restrict__ y,
                                                      signed char* __restrict__ yi,
                                                      float* __restrict__ ysc,
                                                      float alpha, int beta, int wri8) {
    const int wid = threadIdx.x >> 6;
    const int lane = threadIdx.x & 63;
    const int row = blockIdx.x * 4 + wid;
    if (row >= V_NODES) return;
    const int s = rowPtr[row], e_end = rowPtr[row + 1];
    const uint2* __restrict__ xq = (const uint2*)xi;   // 64 x 8B per row

    float acc[8];
    #pragma unroll
    for (int j = 0; j < 8; ++j) acc[j] = 0.f;

    int e = s;
    for (; e + 3 < e_end; e += 4) {
        EPair p[4];
        #pragma unroll
        for (int i = 0; i < 4; ++i) p[i] = ep[e + i];
        float w[4];
        #pragma unroll
        for (int i = 0; i < 4; ++i) w[i] = p[i].w * xsc[p[i].c];
        uint2 q[4];
        #pragma unroll
        for (int i = 0; i < 4; ++i) q[i] = xq[(size_t)p[i].c * 64 + lane];
        #pragma unroll
        for (int i = 0; i < 4; ++i) {
            #pragma unroll
            for (int wd = 0; wd < 2; ++wd) {
                unsigned int uu = wd ? q[i].y : q[i].x;
                #pragma unroll
                for (int b = 0; b < 4; ++b) {
                    float xv = (float)((signed char)(uu >> (8 * b)));
                    acc[wd * 4 + b] += w[i] * xv;
                }
            }
        }
    }
    for (; e < e_end; ++e) {
        EPair p0 = ep[e];
        float w0 = p0.w * xsc[p0.c];
        uint2 q0 = xq[(size_t)p0.c * 64 + lane];
        #pragma unroll
        for (int wd = 0; wd < 2; ++wd) {
            unsigned int uu = wd ? q0.y : q0.x;
            #pragma unroll
            for (int b = 0; b < 4; ++b) {
                float xv = (float)((signed char)(uu >> (8 * b)));
                acc[wd * 4 + b] += w0 * xv;
            }
        }
    }

    float r[8];
    #pragma unroll
    for (int j = 0; j < 8; ++j) r[j] = alpha * acc[j];
    if (beta) {
        uint4 q = ((const uint4*)xold)[(size_t)row * 64 + lane];
        unsigned int u[4] = {q.x, q.y, q.z, q.w};
        #pragma unroll
        for (int j = 0; j < 4; ++j) {
            r[2*j+0] -= bf2f((unsigned short)(u[j] & 0xffffu));
            r[2*j+1] -= bf2f((unsigned short)(u[j] >> 16));
        }
    }
    uint4 o;
    unsigned int* ou = (unsigned int*)&o;
    #pragma unroll
    for (int j = 0; j < 4; ++j)
        ou[j] = (unsigned int)f2bf(r[2*j]) | ((unsigned int)f2bf(r[2*j+1]) << 16);
    ((uint4*)y)[(size_t)row * 64 + lane] = o;

    if (wri8) {
        float m = 0.f;
        #pragma unroll
        for (int j = 0; j < 8; ++j) m = fmaxf(m, fabsf(r[j]));
        #pragma unroll
        for (int off = 1; off < 64; off <<= 1) m = fmaxf(m, __shfl_xor(m, off, 64));
        float inv = (m > 0.f) ? 127.f / m : 0.f;
        unsigned int ow[2] = {0u, 0u};
        #pragma unroll
        for (int j = 0; j < 8; ++j) {
            int si = (int)rintf(r[j] * inv);
            si = max(-127, min(127, si));
            ow[j >> 2] |= ((unsigned int)(si & 0xff)) << (8 * (j & 3));
        }
        uint2 oi; oi.x = ow[0]; oi.y = ow[1];
        ((uint2*)yi)[(size_t)row * 64 + lane] = oi;
        if (lane == 0) ysc[row] = m / 127.f;
    }
}

// ---------------- bf16-gather SpMM (fallback when ws too small) ------------
__global__ __launch_bounds__(256) void spmm_bf16_kernel(const EPair* __restrict__ ep,
                                                        const int* __restrict__ rowPtr,
                                                        const unsigned short* __restrict__ xsrc,
                                                        const unsigned short* __restrict__ xold,
                                                        unsigned short* __restrict__ y,
                                                        float alpha, int beta) {
    const int wid = threadIdx.x >> 6;
    const int lane = threadIdx.x & 63;
    const int row = blockIdx.x * 4 + wid;
    if (row >= V_NODES) return;
    const int s = rowPtr[row], e_end = rowPtr[row + 1];
    const uint4* __restrict__ xs = (const uint4*)xsrc;

    float a0[8], a1[8];
    #pragma unroll
    for (int j = 0; j < 8; ++j) { a0[j] = 0.f; a1[j] = 0.f; }

    int e = s;
    for (; e + 3 < e_end; e += 4) {
        EPair p0 = ep[e], p1 = ep[e+1], p2 = ep[e+2], p3 = ep[e+3];
        uint4 q0 = xs[(size_t)p0.c * 64 + lane];
        uint4 q1 = xs[(size_t)p1.c * 64 + lane];
        uint4 q2 = xs[(size_t)p2.c * 64 + lane];
        uint4 q3 = xs[(size_t)p3.c * 64 + lane];
        unsigned int u0[4] = {q0.x, q0.y, q0.z, q0.w};
        unsigned int u1[4] = {q1.x, q1.y, q1.z, q1.w};
        unsigned int u2[4] = {q2.x, q2.y, q2.z, q2.w};
        unsigned int u3[4] = {q3.x, q3.y, q3.z, q3.w};
        #pragma unroll
        for (int j = 0; j < 4; ++j) {
            a0[2*j+0] += p0.w * bf2f((unsigned short)(u0[j] & 0xffffu));
            a0[2*j+1] += p0.w * bf2f((unsigned short)(u0[j] >> 16));
            a1[2*j+0] += p1.w * bf2f((unsigned short)(u1[j] & 0xffffu));
            a1[2*j+1] += p1.w * bf2f((unsigned short)(u1[j] >> 16));
            a0[2*j+0] += p2.w * bf2f((unsigned short)(u2[j] & 0xffffu));
            a0[2*j+1] += p2.w * bf2f((unsigned short)(u2[j] >> 16));
            a1[2*j+0] += p3.w * bf2f((unsigned short)(u3[j] & 0xffffu));
            a1[2*j+1] += p3.w * bf2f((unsigned short)(u3[j] >> 16));
        }
    }
    for (; e < e_end; ++e) {
        EPair p0 = ep[e];
        uint4 q0 = xs[(size_t)p0.c * 64 + lane];
        unsigned int u0[4] = {q0.x, q0.y, q0.z, q0.w};
        #pragma unroll
        for (int j = 0; j < 4; ++j) {
            a0[2*j+0] += p0.w * bf2f((unsigned short)(u0[j] & 0xffffu));
            a0[2*j+1] += p0.w * bf2f((unsigned short)(u0[j] >> 16));
        }
    }

    float r[8];
    #pragma unroll
    for (int j = 0; j < 8; ++j) r[j] = alpha * (a0[j] + a1[j]);
    if (beta) {
        uint4 q = ((const uint4*)xold)[(size_t)row * 64 + lane];
        unsigned int u[4] = {q.x, q.y, q.z, q.w};
        #pragma unroll
        for (int j = 0; j < 4; ++j) {
            r[2*j+0] -= bf2f((unsigned short)(u[j] & 0xffffu));
            r[2*j+1] -= bf2f((unsigned short)(u[j] >> 16));
        }
    }
    uint4 o;
    unsigned int* ou = (unsigned int*)&o;
    #pragma unroll
    for (int j = 0; j < 4; ++j)
        ou[j] = (unsigned int)f2bf(r[2*j]) | ((unsigned int)f2bf(r[2*j+1]) << 16);
    ((uint4*)y)[(size_t)row * 64 + lane] = o;
}

// ---------------- fused MFMA GEMM over all K orders ------------------------
__global__ __launch_bounds__(256) void gemm_mfma_kernel(const unsigned short* __restrict__ T,
                                                        const unsigned short* __restrict__ WbT,
                                                        const float* __restrict__ bias,
                                                        float* __restrict__ out) {
    __shared__ unsigned short Abuf[2][128 * 64];   // 2 x 16 KB
    const int lane = threadIdx.x & 63;
    const int wv = threadIdx.x >> 6;
    const int v0 = blockIdx.x * 128;
    const int b = blockIdx.y;
    const int lr = lane & 15;
    const int lk = lane >> 4;

    const int lanerow = lane >> 3;
    const int cgp = (lane & 7) ^ lanerow;
    size_t goff[4];
    #pragma unroll
    for (int j = 0; j < 4; ++j) {
        int row_local = wv * 32 + j * 8 + lanerow;
        int rowg = v0 + row_local;
        if (rowg >= V_NODES) rowg = V_NODES - 1;
        goff[j] = (size_t)rowg * FDIM + b * CIN + cgp * 8;
    }

    f32x4 acc[8][2];
    #pragma unroll
    for (int mf = 0; mf < 8; ++mf)
        #pragma unroll
        for (int nf = 0; nf < 2; ++nf)
            acc[mf][nf] = (f32x4){0.f, 0.f, 0.f, 0.f};

    #pragma unroll
    for (int j = 0; j < 4; ++j)
        __builtin_amdgcn_global_load_lds(
            (const __attribute__((address_space(1))) void*)(T + goff[j]),
            (__attribute__((address_space(3))) void*)(&Abuf[0][(wv * 32 + j * 8) * 64]),
            16, 0, 0);
    __syncthreads();

    #pragma unroll 2
    for (int s = 0; s < 10; ++s) {
        const int cur = s & 1;
        if (s < 9) {
            const size_t stepoff = (size_t)((s + 1) >> 1) * V_NODES * FDIM + ((s + 1) & 1) * 64;
            #pragma unroll
            for (int j = 0; j < 4; ++j)
                __builtin_amdgcn_global_load_lds(
                    (const __attribute__((address_space(1))) void*)(T + goff[j] + stepoff),
                    (__attribute__((address_space(3))) void*)(&Abuf[cur ^ 1][(wv * 32 + j * 8) * 64]),
                    16, 0, 0);
        }
        const unsigned short* Ab = &Abuf[cur][0];
        #pragma unroll
        for (int c = 0; c < 2; ++c) {
            s16x8 bfr[2];
            #pragma unroll
            for (int nf = 0; nf < 2; ++nf)
                bfr[nf] = *(const s16x8*)(WbT + (size_t)(wv * 32 + nf * 16 + lr) * KTOT
                                          + s * 64 + c * 32 + lk * 8);
            s16x8 a[8];
            #pragma unroll
            for (int mf = 0; mf < 8; ++mf) {
                int rr = mf * 16 + lr;
                int slot = ((c * 4 + lk) ^ (lr & 7)) * 8;
                a[mf] = *(const s16x8*)(Ab + rr * 64 + slot);
            }
            #pragma unroll
            for (int mf = 0; mf < 8; ++mf)
                #pragma unroll
                for (int nf = 0; nf < 2; ++nf)
                    acc[mf][nf] = __builtin_amdgcn_mfma_f32_16x16x32_bf16(a[mf], bfr[nf], acc[mf][nf], 0, 0, 0);
        }
        __syncthreads();
    }

    float* lds_f = (float*)&Abuf[0][0];
    const float bs0 = bias[wv * 32 + lr];
    const float bs1 = bias[wv * 32 + 16 + lr];
    #pragma unroll
    for (int p = 0; p < 4; ++p) {
        if (wv == p) {
            #pragma unroll
            for (int mf = 0; mf < 8; ++mf)
                #pragma unroll
                for (int nf = 0; nf < 2; ++nf) {
                    int co_l = nf * 16 + lr;
                    int vbase = mf * 16 + lk * 4;
                    f32x4 val = acc[mf][nf];
                    float bs = nf ? bs1 : bs0;
                    val[0] += bs; val[1] += bs; val[2] += bs; val[3] += bs;
                    *(f32x4*)(lds_f + co_l * 132 + vbase) = val;
                }
        }
        __syncthreads();
        #pragma unroll
        for (int i = 0; i < 4; ++i) {
            int flat = i * 256 + threadIdx.x;
            int co_l = flat >> 5;
            int v4 = flat & 31;
            int v = v0 + v4 * 4;
            if (v < V_NODES) {
                f32x4 val = *(const f32x4*)(lds_f + co_l * 132 + v4 * 4);
                *(f32x4*)(out + (size_t)(b * COUT + p * 32 + co_l) * V_NODES + v) = val;
            }
        }
        __syncthreads();
    }
}

extern "C" void kernel_launch(void* const* d_in, const int* in_sizes, int n_in,
                              void* d_out, int out_size, void* d_ws, size_t ws_size,
                              hipStream_t stream) {
    const float* x    = (const float*)d_in[0];
    const float* vals = (const float*)d_in[1];
    const float* W    = (const float*)d_in[2];
    const float* bias = (const float*)d_in[3];
    const int* rows   = (const int*)d_in[4];
    const int* cols   = (const int*)d_in[5];
    const int E = in_sizes[1];
    float* out = (float*)d_out;

    // base workspace layout
    unsigned short* T    = (unsigned short*)d_ws;
    unsigned short* WbT  = T + (size_t)KORD * V_NODES * FDIM;
    EPair* ep     = (EPair*)(WbT + (size_t)COUT * KTOT);
    int*   rowPtr = (int*)(ep + E);
    int*   cursor = rowPtr + V_NODES + 1;
    int*   cnt    = cursor + V_NODES;
    int*   blkSum = cnt + V_NODES;            // SCAN_NBLK
    int*   blkOff = blkSum + SCAN_NBLK;       // SCAN_NBLK
    // optional int8 region (aligned 16)
    char* p8 = (char*)(((uintptr_t)(blkOff + SCAN_NBLK) + 15) & ~(uintptr_t)15);
    signed char* i8A = (signed char*)p8;
    signed char* i8B = i8A + (size_t)V_NODES * FDIM;
    float* scA = (float*)(i8B + (size_t)V_NODES * FDIM);
    float* scB = scA + V_NODES;
    size_t need = (size_t)((char*)(scB + V_NODES) - (char*)d_ws);
    const bool use_i8 = (ws_size >= need);

    unsigned short* T0 = T;
    unsigned short* T1 = T + 1 * (size_t)V_NODES * FDIM;
    unsigned short* T2 = T + 2 * (size_t)V_NODES * FDIM;
    unsigned short* T3 = T + 3 * (size_t)V_NODES * FDIM;
    unsigned short* T4 = T + 4 * (size_t)V_NODES * FDIM;

    const int eBlocks = (E + 255) / 256;
    const int spB4 = (V_NODES + 3) / 4;

    // CSR build (hierarchical scan)
    hipMemsetAsync(cnt, 0, V_NODES * sizeof(int), stream);
    hist_kernel<<<eBlocks, 256, 0, stream>>>(rows, cnt, E);
    scan1_kernel<<<SCAN_NBLK, 256, 0, stream>>>(cnt, rowPtr, blkSum);
    scan2_kernel<<<1, 256, 0, stream>>>(blkSum, blkOff, rowPtr);
    scan3_kernel<<<SCAN_NBLK, 256, 0, stream>>>(rowPtr, blkOff, cursor);
    scatter_kernel<<<eBlocks, 256, 0, stream>>>(vals, rows, cols, cursor, ep, E);

    // T0 + weights
    dim3 tg((V_NODES + 63) / 64, FDIM / 64);
    transpose_kernel<<<tg, 256, 0, stream>>>(x, T0);
    convw_kernel<<<(KTOT * COUT + 255) / 256, 256, 0, stream>>>(W, WbT);

    if (use_i8) {
        quant_rows_kernel<<<spB4, 256, 0, stream>>>(T0, i8A, scA);
        spmm_i8_kernel<<<spB4, 256, 0, stream>>>(ep, rowPtr, i8A, scA, T0, T1, i8B, scB, 1.f, 0, 1);
        spmm_i8_kernel<<<spB4, 256, 0, stream>>>(ep, rowPtr, i8B, scB, T0, T2, i8A, scA, 2.f, 1, 1);
        spmm_i8_kernel<<<spB4, 256, 0, stream>>>(ep, rowPtr, i8A, scA, T1, T3, i8B, scB, 2.f, 1, 1);
        spmm_i8_kernel<<<spB4, 256, 0, stream>>>(ep, rowPtr, i8B, scB, T2, T4, i8A, scA, 2.f, 1, 0);
    } else {
        spmm_bf16_kernel<<<spB4, 256, 0, stream>>>(ep, rowPtr, T0, T0, T1, 1.f, 0);
        spmm_bf16_kernel<<<spB4, 256, 0, stream>>>(ep, rowPtr, T1, T0, T2, 2.f, 1);
        spmm_bf16_kernel<<<spB4, 256, 0, stream>>>(ep, rowPtr, T2, T1, T3, 2.f, 1);
        spmm_bf16_kernel<<<spB4, 256, 0, stream>>>(ep, rowPtr, T3, T2, T4, 2.f, 1);
    }

    // fused contraction over all 5 orders
    dim3 gg((V_NODES + 127) / 128, BATCH);
    gemm_mfma_kernel<<<gg, 256, 0, stream>>>(T, WbT, bias, out);
}

// Round 8
// 579.827 us; speedup vs baseline: 1.4283x; 1.0015x over previous
//
#include <hip/hip_runtime.h>

#define V_NODES 50000
#define FDIM    512   // B*Cin
#define CIN     128
#define COUT    128
#define BATCH   4
#define KORD    5
#define KTOT    (KORD * CIN)   // 640
#define SCAN_NBLK ((V_NODES + 255) / 256)   // 196

typedef short s16x8 __attribute__((ext_vector_type(8)));
typedef float f32x4 __attribute__((ext_vector_type(4)));

struct EPair { float w; int c; };   // interleaved edge: weight + col

__device__ __forceinline__ float bf2f(unsigned short u) {
    union { unsigned int i; float f; } x; x.i = ((unsigned int)u) << 16; return x.f;
}
__device__ __forceinline__ unsigned short f2bf(float f) {
    union { float f; unsigned int i; } x; x.f = f;
    unsigned int r = x.i + 0x7fffu + ((x.i >> 16) & 1u);   // RNE
    return (unsigned short)(r >> 16);
}

// ---------------- transpose: x (512, V) f32 -> T0 (V, 512) bf16 ------------
__global__ __launch_bounds__(256) void transpose_kernel(const float* __restrict__ x,
                                                        unsigned short* __restrict__ t0) {
    __shared__ float tile[64][65];
    const int v0 = blockIdx.x * 64;
    const int r0 = blockIdx.y * 64;
    const int lane = threadIdx.x & 63;
    const int w = threadIdx.x >> 6;
    #pragma unroll
    for (int i = 0; i < 16; ++i) {
        int rr = w * 16 + i;
        int v = v0 + lane;
        tile[rr][lane] = (v < V_NODES) ? x[(size_t)(r0 + rr) * V_NODES + v] : 0.0f;
    }
    __syncthreads();
    #pragma unroll
    for (int i = 0; i < 16; ++i) {
        int vv = w * 16 + i;
        int v = v0 + vv;
        if (v < V_NODES) t0[(size_t)v * FDIM + r0 + lane] = f2bf(tile[lane][vv]);
    }
}

// ---------------- W convert+transpose: W f32 [kci][co] -> WbT bf16 [co][kci]
__global__ __launch_bounds__(256) void convw_kernel(const float* __restrict__ W,
                                                    unsigned short* __restrict__ WbT) {
    int t = blockIdx.x * 256 + threadIdx.x;
    if (t >= KTOT * COUT) return;
    int kci = t >> 7, co = t & 127;
    WbT[(size_t)co * KTOT + kci] = f2bf(W[(size_t)kci * COUT + co]);
}

// ---------------- CSR build ------------------------------------------------
__global__ __launch_bounds__(256) void hist_kernel(const int* __restrict__ rows,
                                                   int* __restrict__ cnt, int E) {
    int e = blockIdx.x * 256 + threadIdx.x;
    if (e < E) atomicAdd(&cnt[rows[e]], 1);
}

// hierarchical scan, phase 1: per-block exclusive scan + block sums
__global__ __launch_bounds__(256) void scan1_kernel(const int* __restrict__ cnt,
                                                    int* __restrict__ rowPtr,
                                                    int* __restrict__ blkSum) {
    __shared__ int sh[256];
    const int t = threadIdx.x;
    const int i = blockIdx.x * 256 + t;
    int v = (i < V_NODES) ? cnt[i] : 0;
    sh[t] = v;
    __syncthreads();
    #pragma unroll
    for (int off = 1; off < 256; off <<= 1) {
        int u = (t >= off) ? sh[t - off] : 0;
        __syncthreads();
        sh[t] += u;
        __syncthreads();
    }
    if (i < V_NODES) rowPtr[i] = sh[t] - v;      // block-local exclusive
    if (t == 255) blkSum[blockIdx.x] = sh[255];
}

// phase 2+3 merged: every block redundantly scans the 196 block sums in LDS,
// picks its own offset, finalizes rowPtr and cursor.
__global__ __launch_bounds__(256) void scan23_kernel(const int* __restrict__ blkSum,
                                                     int* __restrict__ rowPtr,
                                                     int* __restrict__ cursor) {
    __shared__ int sh[256];
    const int t = threadIdx.x;
    int v = (t < SCAN_NBLK) ? blkSum[t] : 0;
    sh[t] = v;
    __syncthreads();
    #pragma unroll
    for (int off = 1; off < 256; off <<= 1) {
        int u = (t >= off) ? sh[t - off] : 0;
        __syncthreads();
        sh[t] += u;
        __syncthreads();
    }
    const int boff = sh[blockIdx.x] - blkSum[blockIdx.x];   // exclusive offset
    const int i = blockIdx.x * 256 + t;
    if (i < V_NODES) {
        int r = rowPtr[i] + boff;
        rowPtr[i] = r;
        cursor[i] = r;
    }
    if (blockIdx.x == 0 && t == 255) rowPtr[V_NODES] = sh[255];
}

__global__ __launch_bounds__(256) void scatter_kernel(const float* __restrict__ vals,
                                                      const int* __restrict__ rows,
                                                      const int* __restrict__ cols,
                                                      int* __restrict__ cursor,
                                                      EPair* __restrict__ ep, int E) {
    int e = blockIdx.x * 256 + threadIdx.x;
    if (e >= E) return;
    int r = rows[e];
    int pos = atomicAdd(&cursor[r], 1);
    EPair p; p.w = vals[e]; p.c = cols[e];
    ep[pos] = p;
}

// ---------------- quantize bf16 rows -> int8 + per-row scale ---------------
__global__ __launch_bounds__(256) void quant_rows_kernel(const unsigned short* __restrict__ xb,
                                                         signed char* __restrict__ xi,
                                                         float* __restrict__ xs) {
    const int wid = threadIdx.x >> 6;
    const int lane = threadIdx.x & 63;
    const int row = blockIdx.x * 4 + wid;
    if (row >= V_NODES) return;
    uint4 q = ((const uint4*)xb)[(size_t)row * 64 + lane];
    unsigned int u[4] = {q.x, q.y, q.z, q.w};
    float f[8];
    #pragma unroll
    for (int j = 0; j < 4; ++j) {
        f[2*j+0] = bf2f((unsigned short)(u[j] & 0xffffu));
        f[2*j+1] = bf2f((unsigned short)(u[j] >> 16));
    }
    float m = 0.f;
    #pragma unroll
    for (int j = 0; j < 8; ++j) m = fmaxf(m, fabsf(f[j]));
    #pragma unroll
    for (int off = 1; off < 64; off <<= 1) m = fmaxf(m, __shfl_xor(m, off, 64));
    float inv = (m > 0.f) ? 127.f / m : 0.f;
    uint2 o; unsigned int ow[2] = {0u, 0u};
    #pragma unroll
    for (int j = 0; j < 8; ++j) {
        int si = (int)rintf(f[j] * inv);
        si = max(-127, min(127, si));
        ow[j >> 2] |= ((unsigned int)(si & 0xff)) << (8 * (j & 3));
    }
    o.x = ow[0]; o.y = ow[1];
    ((uint2*)xi)[(size_t)row * 64 + lane] = o;
    if (lane == 0) xs[row] = m / 127.f;
}

// ---------------- CSR SpMM from int8 source --------------------------------
__global__ __launch_bounds__(256) void spmm_i8_kernel(const EPair* __restrict__ ep,
                                                      const int* __restrict__ rowPtr,
                                                      const signed char* __restrict__ xi,
                                                      const float* __restrict__ xsc,
                                                      const unsigned short* __restrict__ xold,
                                                      unsigned short* __restrict__ y,
                                                      signed char* __restrict__ yi,
                                                      float* __restrict__ ysc,
                                                      float alpha, int beta, int wri8) {
    const int wid = threadIdx.x >> 6;
    const int lane = threadIdx.x & 63;
    const int row = blockIdx.x * 4 + wid;
    if (row >= V_NODES) return;
    const int s = rowPtr[row], e_end = rowPtr[row + 1];
    const uint2* __restrict__ xq = (const uint2*)xi;   // 64 x 8B per row

    float acc[8];
    #pragma unroll
    for (int j = 0; j < 8; ++j) acc[j] = 0.f;

    int e = s;
    for (; e + 3 < e_end; e += 4) {
        EPair p[4];
        #pragma unroll
        for (int i = 0; i < 4; ++i) p[i] = ep[e + i];
        float w[4];
        #pragma unroll
        for (int i = 0; i < 4; ++i) w[i] = p[i].w * xsc[p[i].c];
        uint2 q[4];
        #pragma unroll
        for (int i = 0; i < 4; ++i) q[i] = xq[(size_t)p[i].c * 64 + lane];
        #pragma unroll
        for (int i = 0; i < 4; ++i) {
            #pragma unroll
            for (int wd = 0; wd < 2; ++wd) {
                unsigned int uu = wd ? q[i].y : q[i].x;
                #pragma unroll
                for (int b = 0; b < 4; ++b) {
                    float xv = (float)((signed char)(uu >> (8 * b)));
                    acc[wd * 4 + b] += w[i] * xv;
                }
            }
        }
    }
    for (; e < e_end; ++e) {
        EPair p0 = ep[e];
        float w0 = p0.w * xsc[p0.c];
        uint2 q0 = xq[(size_t)p0.c * 64 + lane];
        #pragma unroll
        for (int wd = 0; wd < 2; ++wd) {
            unsigned int uu = wd ? q0.y : q0.x;
            #pragma unroll
            for (int b = 0; b < 4; ++b) {
                float xv = (float)((signed char)(uu >> (8 * b)));
                acc[wd * 4 + b] += w0 * xv;
            }
        }
    }

    float r[8];
    #pragma unroll
    for (int j = 0; j < 8; ++j) r[j] = alpha * acc[j];
    if (beta) {
        uint4 q = ((const uint4*)xold)[(size_t)row * 64 + lane];
        unsigned int u[4] = {q.x, q.y, q.z, q.w};
        #pragma unroll
        for (int j = 0; j < 4; ++j) {
            r[2*j+0] -= bf2f((unsigned short)(u[j] & 0xffffu));
            r[2*j+1] -= bf2f((unsigned short)(u[j] >> 16));
        }
    }
    uint4 o;
    unsigned int* ou = (unsigned int*)&o;
    #pragma unroll
    for (int j = 0; j < 4; ++j)
        ou[j] = (unsigned int)f2bf(r[2*j]) | ((unsigned int)f2bf(r[2*j+1]) << 16);
    ((uint4*)y)[(size_t)row * 64 + lane] = o;

    if (wri8) {
        float m = 0.f;
        #pragma unroll
        for (int j = 0; j < 8; ++j) m = fmaxf(m, fabsf(r[j]));
        #pragma unroll
        for (int off = 1; off < 64; off <<= 1) m = fmaxf(m, __shfl_xor(m, off, 64));
        float inv = (m > 0.f) ? 127.f / m : 0.f;
        unsigned int ow[2] = {0u, 0u};
        #pragma unroll
        for (int j = 0; j < 8; ++j) {
            int si = (int)rintf(r[j] * inv);
            si = max(-127, min(127, si));
            ow[j >> 2] |= ((unsigned int)(si & 0xff)) << (8 * (j & 3));
        }
        uint2 oi; oi.x = ow[0]; oi.y = ow[1];
        ((uint2*)yi)[(size_t)row * 64 + lane] = oi;
        if (lane == 0) ysc[row] = m / 127.f;
    }
}

// ---------------- bf16-gather SpMM (fallback when ws too small) ------------
__global__ __launch_bounds__(256) void spmm_bf16_kernel(const EPair* __restrict__ ep,
                                                        const int* __restrict__ rowPtr,
                                                        const unsigned short* __restrict__ xsrc,
                                                        const unsigned short* __restrict__ xold,
                                                        unsigned short* __restrict__ y,
                                                        float alpha, int beta) {
    const int wid = threadIdx.x >> 6;
    const int lane = threadIdx.x & 63;
    const int row = blockIdx.x * 4 + wid;
    if (row >= V_NODES) return;
    const int s = rowPtr[row], e_end = rowPtr[row + 1];
    const uint4* __restrict__ xs = (const uint4*)xsrc;

    float a0[8], a1[8];
    #pragma unroll
    for (int j = 0; j < 8; ++j) { a0[j] = 0.f; a1[j] = 0.f; }

    int e = s;
    for (; e + 3 < e_end; e += 4) {
        EPair p0 = ep[e], p1 = ep[e+1], p2 = ep[e+2], p3 = ep[e+3];
        uint4 q0 = xs[(size_t)p0.c * 64 + lane];
        uint4 q1 = xs[(size_t)p1.c * 64 + lane];
        uint4 q2 = xs[(size_t)p2.c * 64 + lane];
        uint4 q3 = xs[(size_t)p3.c * 64 + lane];
        unsigned int u0[4] = {q0.x, q0.y, q0.z, q0.w};
        unsigned int u1[4] = {q1.x, q1.y, q1.z, q1.w};
        unsigned int u2[4] = {q2.x, q2.y, q2.z, q2.w};
        unsigned int u3[4] = {q3.x, q3.y, q3.z, q3.w};
        #pragma unroll
        for (int j = 0; j < 4; ++j) {
            a0[2*j+0] += p0.w * bf2f((unsigned short)(u0[j] & 0xffffu));
            a0[2*j+1] += p0.w * bf2f((unsigned short)(u0[j] >> 16));
            a1[2*j+0] += p1.w * bf2f((unsigned short)(u1[j] & 0xffffu));
            a1[2*j+1] += p1.w * bf2f((unsigned short)(u1[j] >> 16));
            a0[2*j+0] += p2.w * bf2f((unsigned short)(u2[j] & 0xffffu));
            a0[2*j+1] += p2.w * bf2f((unsigned short)(u2[j] >> 16));
            a1[2*j+0] += p3.w * bf2f((unsigned short)(u3[j] & 0xffffu));
            a1[2*j+1] += p3.w * bf2f((unsigned short)(u3[j] >> 16));
        }
    }
    for (; e < e_end; ++e) {
        EPair p0 = ep[e];
        uint4 q0 = xs[(size_t)p0.c * 64 + lane];
        unsigned int u0[4] = {q0.x, q0.y, q0.z, q0.w};
        #pragma unroll
        for (int j = 0; j < 4; ++j) {
            a0[2*j+0] += p0.w * bf2f((unsigned short)(u0[j] & 0xffffu));
            a0[2*j+1] += p0.w * bf2f((unsigned short)(u0[j] >> 16));
        }
    }

    float r[8];
    #pragma unroll
    for (int j = 0; j < 8; ++j) r[j] = alpha * (a0[j] + a1[j]);
    if (beta) {
        uint4 q = ((const uint4*)xold)[(size_t)row * 64 + lane];
        unsigned int u[4] = {q.x, q.y, q.z, q.w};
        #pragma unroll
        for (int j = 0; j < 4; ++j) {
            r[2*j+0] -= bf2f((unsigned short)(u[j] & 0xffffu));
            r[2*j+1] -= bf2f((unsigned short)(u[j] >> 16));
        }
    }
    uint4 o;
    unsigned int* ou = (unsigned int*)&o;
    #pragma unroll
    for (int j = 0; j < 4; ++j)
        ou[j] = (unsigned int)f2bf(r[2*j]) | ((unsigned int)f2bf(r[2*j+1]) << 16);
    ((uint4*)y)[(size_t)row * 64 + lane] = o;
}

// ---------------- fused MFMA GEMM over all K orders ------------------------
// A via double-buffered LDS (global_load_lds, swizzled); B fragments register-
// prefetched one K-step ahead to hide L2 latency.
__global__ __launch_bounds__(256) void gemm_mfma_kernel(const unsigned short* __restrict__ T,
                                                        const unsigned short* __restrict__ WbT,
                                                        const float* __restrict__ bias,
                                                        float* __restrict__ out) {
    __shared__ unsigned short Abuf[2][128 * 64];   // 2 x 16 KB
    const int lane = threadIdx.x & 63;
    const int wv = threadIdx.x >> 6;
    const int v0 = blockIdx.x * 128;
    const int b = blockIdx.y;
    const int lr = lane & 15;
    const int lk = lane >> 4;

    const int lanerow = lane >> 3;
    const int cgp = (lane & 7) ^ lanerow;
    size_t goff[4];
    #pragma unroll
    for (int j = 0; j < 4; ++j) {
        int row_local = wv * 32 + j * 8 + lanerow;
        int rowg = v0 + row_local;
        if (rowg >= V_NODES) rowg = V_NODES - 1;
        goff[j] = (size_t)rowg * FDIM + b * CIN + cgp * 8;
    }

    f32x4 acc[8][2];
    #pragma unroll
    for (int mf = 0; mf < 8; ++mf)
        #pragma unroll
        for (int nf = 0; nf < 2; ++nf)
            acc[mf][nf] = (f32x4){0.f, 0.f, 0.f, 0.f};

    // B fragment base for this lane; fragment (s,c,nf) at + nf*16*KTOT + s*64 + c*32
    const unsigned short* Bb = WbT + (size_t)(wv * 32 + lr) * KTOT + lk * 8;
    s16x8 bcur[2][2];
    #pragma unroll
    for (int c = 0; c < 2; ++c)
        #pragma unroll
        for (int nf = 0; nf < 2; ++nf)
            bcur[c][nf] = *(const s16x8*)(Bb + (size_t)nf * 16 * KTOT + c * 32);

    // prologue: stage A step 0 into buf 0
    #pragma unroll
    for (int j = 0; j < 4; ++j)
        __builtin_amdgcn_global_load_lds(
            (const __attribute__((address_space(1))) void*)(T + goff[j]),
            (__attribute__((address_space(3))) void*)(&Abuf[0][(wv * 32 + j * 8) * 64]),
            16, 0, 0);
    __syncthreads();

    #pragma unroll 2
    for (int s = 0; s < 10; ++s) {
        const int cur = s & 1;
        s16x8 bnxt[2][2];
        if (s < 9) {
            const size_t stepoff = (size_t)((s + 1) >> 1) * V_NODES * FDIM + ((s + 1) & 1) * 64;
            #pragma unroll
            for (int j = 0; j < 4; ++j)
                __builtin_amdgcn_global_load_lds(
                    (const __attribute__((address_space(1))) void*)(T + goff[j] + stepoff),
                    (__attribute__((address_space(3))) void*)(&Abuf[cur ^ 1][(wv * 32 + j * 8) * 64]),
                    16, 0, 0);
            #pragma unroll
            for (int c = 0; c < 2; ++c)
                #pragma unroll
                for (int nf = 0; nf < 2; ++nf)
                    bnxt[c][nf] = *(const s16x8*)(Bb + (size_t)nf * 16 * KTOT + (s + 1) * 64 + c * 32);
        }
        const unsigned short* Ab = &Abuf[cur][0];
        #pragma unroll
        for (int c = 0; c < 2; ++c) {
            s16x8 a[8];
            #pragma unroll
            for (int mf = 0; mf < 8; ++mf) {
                int rr = mf * 16 + lr;
                int slot = ((c * 4 + lk) ^ (lr & 7)) * 8;
                a[mf] = *(const s16x8*)(Ab + rr * 64 + slot);
            }
            #pragma unroll
            for (int mf = 0; mf < 8; ++mf)
                #pragma unroll
                for (int nf = 0; nf < 2; ++nf)
                    acc[mf][nf] = __builtin_amdgcn_mfma_f32_16x16x32_bf16(a[mf], bcur[c][nf], acc[mf][nf], 0, 0, 0);
        }
        if (s < 9) {
            #pragma unroll
            for (int c = 0; c < 2; ++c)
                #pragma unroll
                for (int nf = 0; nf < 2; ++nf)
                    bcur[c][nf] = bnxt[c][nf];
        }
        __syncthreads();
    }

    float* lds_f = (float*)&Abuf[0][0];
    const float bs0 = bias[wv * 32 + lr];
    const float bs1 = bias[wv * 32 + 16 + lr];
    #pragma unroll
    for (int p = 0; p < 4; ++p) {
        if (wv == p) {
            #pragma unroll
            for (int mf = 0; mf < 8; ++mf)
                #pragma unroll
                for (int nf = 0; nf < 2; ++nf) {
                    int co_l = nf * 16 + lr;
                    int vbase = mf * 16 + lk * 4;
                    f32x4 val = acc[mf][nf];
                    float bs = nf ? bs1 : bs0;
                    val[0] += bs; val[1] += bs; val[2] += bs; val[3] += bs;
                    *(f32x4*)(lds_f + co_l * 132 + vbase) = val;
                }
        }
        __syncthreads();
        #pragma unroll
        for (int i = 0; i < 4; ++i) {
            int flat = i * 256 + threadIdx.x;
            int co_l = flat >> 5;
            int v4 = flat & 31;
            int v = v0 + v4 * 4;
            if (v < V_NODES) {
                f32x4 val = *(const f32x4*)(lds_f + co_l * 132 + v4 * 4);
                *(f32x4*)(out + (size_t)(b * COUT + p * 32 + co_l) * V_NODES + v) = val;
            }
        }
        __syncthreads();
    }
}

extern "C" void kernel_launch(void* const* d_in, const int* in_sizes, int n_in,
                              void* d_out, int out_size, void* d_ws, size_t ws_size,
                              hipStream_t stream) {
    const float* x    = (const float*)d_in[0];
    const float* vals = (const float*)d_in[1];
    const float* W    = (const float*)d_in[2];
    const float* bias = (const float*)d_in[3];
    const int* rows   = (const int*)d_in[4];
    const int* cols   = (const int*)d_in[5];
    const int E = in_sizes[1];
    float* out = (float*)d_out;

    // base workspace layout
    unsigned short* T    = (unsigned short*)d_ws;
    unsigned short* WbT  = T + (size_t)KORD * V_NODES * FDIM;
    EPair* ep     = (EPair*)(WbT + (size_t)COUT * KTOT);
    int*   rowPtr = (int*)(ep + E);
    int*   cursor = rowPtr + V_NODES + 1;
    int*   cnt    = cursor + V_NODES;
    int*   blkSum = cnt + V_NODES;            // SCAN_NBLK
    // optional int8 region (aligned 16)
    char* p8 = (char*)(((uintptr_t)(blkSum + SCAN_NBLK) + 15) & ~(uintptr_t)15);
    signed char* i8A = (signed char*)p8;
    signed char* i8B = i8A + (size_t)V_NODES * FDIM;
    float* scA = (float*)(i8B + (size_t)V_NODES * FDIM);
    float* scB = scA + V_NODES;
    size_t need = (size_t)((char*)(scB + V_NODES) - (char*)d_ws);
    const bool use_i8 = (ws_size >= need);

    unsigned short* T0 = T;
    unsigned short* T1 = T + 1 * (size_t)V_NODES * FDIM;
    unsigned short* T2 = T + 2 * (size_t)V_NODES * FDIM;
    unsigned short* T3 = T + 3 * (size_t)V_NODES * FDIM;
    unsigned short* T4 = T + 4 * (size_t)V_NODES * FDIM;

    const int eBlocks = (E + 255) / 256;
    const int spB4 = (V_NODES + 3) / 4;

    // CSR build (hierarchical scan, 2 dispatches)
    hipMemsetAsync(cnt, 0, V_NODES * sizeof(int), stream);
    hist_kernel<<<eBlocks, 256, 0, stream>>>(rows, cnt, E);
    scan1_kernel<<<SCAN_NBLK, 256, 0, stream>>>(cnt, rowPtr, blkSum);
    scan23_kernel<<<SCAN_NBLK, 256, 0, stream>>>(blkSum, rowPtr, cursor);
    scatter_kernel<<<eBlocks, 256, 0, stream>>>(vals, rows, cols, cursor, ep, E);

    // T0 + weights
    dim3 tg((V_NODES + 63) / 64, FDIM / 64);
    transpose_kernel<<<tg, 256, 0, stream>>>(x, T0);
    convw_kernel<<<(KTOT * COUT + 255) / 256, 256, 0, stream>>>(W, WbT);

    if (use_i8) {
        quant_rows_kernel<<<spB4, 256, 0, stream>>>(T0, i8A, scA);
        spmm_i8_kernel<<<spB4, 256, 0, stream>>>(ep, rowPtr, i8A, scA, T0, T1, i8B, scB, 1.f, 0, 1);
        spmm_i8_kernel<<<spB4, 256, 0, stream>>>(ep, rowPtr, i8B, scB, T0, T2, i8A, scA, 2.f, 1, 1);
        spmm_i8_kernel<<<spB4, 256, 0, stream>>>(ep, rowPtr, i8A, scA, T1, T3, i8B, scB, 2.f, 1, 1);
        spmm_i8_kernel<<<spB4, 256, 0, stream>>>(ep, rowPtr, i8B, scB, T2, T4, i8A, scA, 2.f, 1, 0);
    } else {
        spmm_bf16_kernel<<<spB4, 256, 0, stream>>>(ep, rowPtr, T0, T0, T1, 1.f, 0);
        spmm_bf16_kernel<<<spB4, 256, 0, stream>>>(ep, rowPtr, T1, T0, T2, 2.f, 1);
        spmm_bf16_kernel<<<spB4, 256, 0, stream>>>(ep, rowPtr, T2, T1, T3, 2.f, 1);
        spmm_bf16_kernel<<<spB4, 256, 0, stream>>>(ep, rowPtr, T3, T2, T4, 2.f, 1);
    }

    // fused contraction over all 5 orders
    dim3 gg((V_NODES + 127) / 128, BATCH);
    gemm_mfma_kernel<<<gg, 256, 0, stream>>>(T, WbT, bias, out);
}

// Round 9
// 571.123 us; speedup vs baseline: 1.4501x; 1.0152x over previous
//
#include <hip/hip_runtime.h>

#define V_NODES 50000
#define FDIM    512   // B*Cin
#define CIN     128
#define COUT    128
#define BATCH   4
#define KORD    5
#define KTOT    (KORD * CIN)   // 640
#define SCAN_NBLK ((V_NODES + 255) / 256)   // 196

typedef short s16x8 __attribute__((ext_vector_type(8)));
typedef float f32x4 __attribute__((ext_vector_type(4)));

struct EPair { float w; int c; };   // interleaved edge: weight + col

__device__ __forceinline__ float bf2f(unsigned short u) {
    union { unsigned int i; float f; } x; x.i = ((unsigned int)u) << 16; return x.f;
}
__device__ __forceinline__ unsigned short f2bf(float f) {
    union { float f; unsigned int i; } x; x.f = f;
    unsigned int r = x.i + 0x7fffu + ((x.i >> 16) & 1u);   // RNE
    return (unsigned short)(r >> 16);
}

// ---------------- transpose: x (512, V) f32 -> T0 (V, 512) bf16 ------------
__global__ __launch_bounds__(256) void transpose_kernel(const float* __restrict__ x,
                                                        unsigned short* __restrict__ t0) {
    __shared__ float tile[64][65];
    const int v0 = blockIdx.x * 64;
    const int r0 = blockIdx.y * 64;
    const int lane = threadIdx.x & 63;
    const int w = threadIdx.x >> 6;
    #pragma unroll
    for (int i = 0; i < 16; ++i) {
        int rr = w * 16 + i;
        int v = v0 + lane;
        tile[rr][lane] = (v < V_NODES) ? x[(size_t)(r0 + rr) * V_NODES + v] : 0.0f;
    }
    __syncthreads();
    #pragma unroll
    for (int i = 0; i < 16; ++i) {
        int vv = w * 16 + i;
        int v = v0 + vv;
        if (v < V_NODES) t0[(size_t)v * FDIM + r0 + lane] = f2bf(tile[lane][vv]);
    }
}

// ---------------- W convert+transpose: W f32 [kci][co] -> WbT bf16 [co][kci]
__global__ __launch_bounds__(256) void convw_kernel(const float* __restrict__ W,
                                                    unsigned short* __restrict__ WbT) {
    int t = blockIdx.x * 256 + threadIdx.x;
    if (t >= KTOT * COUT) return;
    int kci = t >> 7, co = t & 127;
    WbT[(size_t)co * KTOT + kci] = f2bf(W[(size_t)kci * COUT + co]);
}

// ---------------- CSR build ------------------------------------------------
__global__ __launch_bounds__(256) void hist_kernel(const int* __restrict__ rows,
                                                   int* __restrict__ cnt, int E) {
    int e = blockIdx.x * 256 + threadIdx.x;
    if (e < E) atomicAdd(&cnt[rows[e]], 1);
}

// hierarchical scan, phase 1: per-block exclusive scan + block sums
__global__ __launch_bounds__(256) void scan1_kernel(const int* __restrict__ cnt,
                                                    int* __restrict__ rowPtr,
                                                    int* __restrict__ blkSum) {
    __shared__ int sh[256];
    const int t = threadIdx.x;
    const int i = blockIdx.x * 256 + t;
    int v = (i < V_NODES) ? cnt[i] : 0;
    sh[t] = v;
    __syncthreads();
    #pragma unroll
    for (int off = 1; off < 256; off <<= 1) {
        int u = (t >= off) ? sh[t - off] : 0;
        __syncthreads();
        sh[t] += u;
        __syncthreads();
    }
    if (i < V_NODES) rowPtr[i] = sh[t] - v;      // block-local exclusive
    if (t == 255) blkSum[blockIdx.x] = sh[255];
}

// phase 2+3 merged: every block redundantly scans the 196 block sums in LDS,
// picks its own offset, finalizes rowPtr and cursor.
__global__ __launch_bounds__(256) void scan23_kernel(const int* __restrict__ blkSum,
                                                     int* __restrict__ rowPtr,
                                                     int* __restrict__ cursor) {
    __shared__ int sh[256];
    const int t = threadIdx.x;
    int v = (t < SCAN_NBLK) ? blkSum[t] : 0;
    sh[t] = v;
    __syncthreads();
    #pragma unroll
    for (int off = 1; off < 256; off <<= 1) {
        int u = (t >= off) ? sh[t - off] : 0;
        __syncthreads();
        sh[t] += u;
        __syncthreads();
    }
    const int boff = sh[blockIdx.x] - blkSum[blockIdx.x];   // exclusive offset
    const int i = blockIdx.x * 256 + t;
    if (i < V_NODES) {
        int r = rowPtr[i] + boff;
        rowPtr[i] = r;
        cursor[i] = r;
    }
    if (blockIdx.x == 0 && t == 255) rowPtr[V_NODES] = sh[255];
}

__global__ __launch_bounds__(256) void scatter_kernel(const float* __restrict__ vals,
                                                      const int* __restrict__ rows,
                                                      const int* __restrict__ cols,
                                                      int* __restrict__ cursor,
                                                      EPair* __restrict__ ep, int E) {
    int e = blockIdx.x * 256 + threadIdx.x;
    if (e >= E) return;
    int r = rows[e];
    int pos = atomicAdd(&cursor[r], 1);
    EPair p; p.w = vals[e]; p.c = cols[e];
    ep[pos] = p;
}

// ---------------- quantize bf16 rows -> int8 + per-row scale ---------------
__global__ __launch_bounds__(256) void quant_rows_kernel(const unsigned short* __restrict__ xb,
                                                         signed char* __restrict__ xi,
                                                         float* __restrict__ xs) {
    const int wid = threadIdx.x >> 6;
    const int lane = threadIdx.x & 63;
    const int row = blockIdx.x * 4 + wid;
    if (row >= V_NODES) return;
    uint4 q = ((const uint4*)xb)[(size_t)row * 64 + lane];
    unsigned int u[4] = {q.x, q.y, q.z, q.w};
    float f[8];
    #pragma unroll
    for (int j = 0; j < 4; ++j) {
        f[2*j+0] = bf2f((unsigned short)(u[j] & 0xffffu));
        f[2*j+1] = bf2f((unsigned short)(u[j] >> 16));
    }
    float m = 0.f;
    #pragma unroll
    for (int j = 0; j < 8; ++j) m = fmaxf(m, fabsf(f[j]));
    #pragma unroll
    for (int off = 1; off < 64; off <<= 1) m = fmaxf(m, __shfl_xor(m, off, 64));
    float inv = (m > 0.f) ? 127.f / m : 0.f;
    uint2 o; unsigned int ow[2] = {0u, 0u};
    #pragma unroll
    for (int j = 0; j < 8; ++j) {
        int si = (int)rintf(f[j] * inv);
        si = max(-127, min(127, si));
        ow[j >> 2] |= ((unsigned int)(si & 0xff)) << (8 * (j & 3));
    }
    o.x = ow[0]; o.y = ow[1];
    ((uint2*)xi)[(size_t)row * 64 + lane] = o;
    if (lane == 0) xs[row] = m / 127.f;
}

// ---------------- CSR SpMM from int8 source --------------------------------
__global__ __launch_bounds__(256) void spmm_i8_kernel(const EPair* __restrict__ ep,
                                                      const int* __restrict__ rowPtr,
                                                      const signed char* __restrict__ xi,
                                                      const float* __restrict__ xsc,
                                                      const unsigned short* __restrict__ xold,
                                                      unsigned short* __restrict__ y,
                                                      signed char* __restrict__ yi,
                                                      float* __restrict__ ysc,
                                                      float alpha, int beta, int wri8) {
    const int wid = threadIdx.x >> 6;
    const int lane = threadIdx.x & 63;
    const int row = blockIdx.x * 4 + wid;
    if (row >= V_NODES) return;
    const int s = rowPtr[row], e_end = rowPtr[row + 1];
    const uint2* __restrict__ xq = (const uint2*)xi;   // 64 x 8B per row

    float acc[8];
    #pragma unroll
    for (int j = 0; j < 8; ++j) acc[j] = 0.f;

    int e = s;
    for (; e + 3 < e_end; e += 4) {
        EPair p[4];
        #pragma unroll
        for (int i = 0; i < 4; ++i) p[i] = ep[e + i];
        float w[4];
        #pragma unroll
        for (int i = 0; i < 4; ++i) w[i] = p[i].w * xsc[p[i].c];
        uint2 q[4];
        #pragma unroll
        for (int i = 0; i < 4; ++i) q[i] = xq[(size_t)p[i].c * 64 + lane];
        #pragma unroll
        for (int i = 0; i < 4; ++i) {
            #pragma unroll
            for (int wd = 0; wd < 2; ++wd) {
                unsigned int uu = wd ? q[i].y : q[i].x;
                #pragma unroll
                for (int b = 0; b < 4; ++b) {
                    float xv = (float)((signed char)(uu >> (8 * b)));
                    acc[wd * 4 + b] += w[i] * xv;
                }
            }
        }
    }
    for (; e < e_end; ++e) {
        EPair p0 = ep[e];
        float w0 = p0.w * xsc[p0.c];
        uint2 q0 = xq[(size_t)p0.c * 64 + lane];
        #pragma unroll
        for (int wd = 0; wd < 2; ++wd) {
            unsigned int uu = wd ? q0.y : q0.x;
            #pragma unroll
            for (int b = 0; b < 4; ++b) {
                float xv = (float)((signed char)(uu >> (8 * b)));
                acc[wd * 4 + b] += w0 * xv;
            }
        }
    }

    float r[8];
    #pragma unroll
    for (int j = 0; j < 8; ++j) r[j] = alpha * acc[j];
    if (beta) {
        uint4 q = ((const uint4*)xold)[(size_t)row * 64 + lane];
        unsigned int u[4] = {q.x, q.y, q.z, q.w};
        #pragma unroll
        for (int j = 0; j < 4; ++j) {
            r[2*j+0] -= bf2f((unsigned short)(u[j] & 0xffffu));
            r[2*j+1] -= bf2f((unsigned short)(u[j] >> 16));
        }
    }
    uint4 o;
    unsigned int* ou = (unsigned int*)&o;
    #pragma unroll
    for (int j = 0; j < 4; ++j)
        ou[j] = (unsigned int)f2bf(r[2*j]) | ((unsigned int)f2bf(r[2*j+1]) << 16);
    ((uint4*)y)[(size_t)row * 64 + lane] = o;

    if (wri8) {
        float m = 0.f;
        #pragma unroll
        for (int j = 0; j < 8; ++j) m = fmaxf(m, fabsf(r[j]));
        #pragma unroll
        for (int off = 1; off < 64; off <<= 1) m = fmaxf(m, __shfl_xor(m, off, 64));
        float inv = (m > 0.f) ? 127.f / m : 0.f;
        unsigned int ow[2] = {0u, 0u};
        #pragma unroll
        for (int j = 0; j < 8; ++j) {
            int si = (int)rintf(r[j] * inv);
            si = max(-127, min(127, si));
            ow[j >> 2] |= ((unsigned int)(si & 0xff)) << (8 * (j & 3));
        }
        uint2 oi; oi.x = ow[0]; oi.y = ow[1];
        ((uint2*)yi)[(size_t)row * 64 + lane] = oi;
        if (lane == 0) ysc[row] = m / 127.f;
    }
}

// ---------------- bf16-gather SpMM (fallback when ws too small) ------------
__global__ __launch_bounds__(256) void spmm_bf16_kernel(const EPair* __restrict__ ep,
                                                        const int* __restrict__ rowPtr,
                                                        const unsigned short* __restrict__ xsrc,
                                                        const unsigned short* __restrict__ xold,
                                                        unsigned short* __restrict__ y,
                                                        float alpha, int beta) {
    const int wid = threadIdx.x >> 6;
    const int lane = threadIdx.x & 63;
    const int row = blockIdx.x * 4 + wid;
    if (row >= V_NODES) return;
    const int s = rowPtr[row], e_end = rowPtr[row + 1];
    const uint4* __restrict__ xs = (const uint4*)xsrc;

    float a0[8], a1[8];
    #pragma unroll
    for (int j = 0; j < 8; ++j) { a0[j] = 0.f; a1[j] = 0.f; }

    int e = s;
    for (; e + 3 < e_end; e += 4) {
        EPair p0 = ep[e], p1 = ep[e+1], p2 = ep[e+2], p3 = ep[e+3];
        uint4 q0 = xs[(size_t)p0.c * 64 + lane];
        uint4 q1 = xs[(size_t)p1.c * 64 + lane];
        uint4 q2 = xs[(size_t)p2.c * 64 + lane];
        uint4 q3 = xs[(size_t)p3.c * 64 + lane];
        unsigned int u0[4] = {q0.x, q0.y, q0.z, q0.w};
        unsigned int u1[4] = {q1.x, q1.y, q1.z, q1.w};
        unsigned int u2[4] = {q2.x, q2.y, q2.z, q2.w};
        unsigned int u3[4] = {q3.x, q3.y, q3.z, q3.w};
        #pragma unroll
        for (int j = 0; j < 4; ++j) {
            a0[2*j+0] += p0.w * bf2f((unsigned short)(u0[j] & 0xffffu));
            a0[2*j+1] += p0.w * bf2f((unsigned short)(u0[j] >> 16));
            a1[2*j+0] += p1.w * bf2f((unsigned short)(u1[j] & 0xffffu));
            a1[2*j+1] += p1.w * bf2f((unsigned short)(u1[j] >> 16));
            a0[2*j+0] += p2.w * bf2f((unsigned short)(u2[j] & 0xffffu));
            a0[2*j+1] += p2.w * bf2f((unsigned short)(u2[j] >> 16));
            a1[2*j+0] += p3.w * bf2f((unsigned short)(u3[j] & 0xffffu));
            a1[2*j+1] += p3.w * bf2f((unsigned short)(u3[j] >> 16));
        }
    }
    for (; e < e_end; ++e) {
        EPair p0 = ep[e];
        uint4 q0 = xs[(size_t)p0.c * 64 + lane];
        unsigned int u0[4] = {q0.x, q0.y, q0.z, q0.w};
        #pragma unroll
        for (int j = 0; j < 4; ++j) {
            a0[2*j+0] += p0.w * bf2f((unsigned short)(u0[j] & 0xffffu));
            a0[2*j+1] += p0.w * bf2f((unsigned short)(u0[j] >> 16));
        }
    }

    float r[8];
    #pragma unroll
    for (int j = 0; j < 8; ++j) r[j] = alpha * (a0[j] + a1[j]);
    if (beta) {
        uint4 q = ((const uint4*)xold)[(size_t)row * 64 + lane];
        unsigned int u[4] = {q.x, q.y, q.z, q.w};
        #pragma unroll
        for (int j = 0; j < 4; ++j) {
            r[2*j+0] -= bf2f((unsigned short)(u[j] & 0xffffu));
            r[2*j+1] -= bf2f((unsigned short)(u[j] >> 16));
        }
    }
    uint4 o;
    unsigned int* ou = (unsigned int*)&o;
    #pragma unroll
    for (int j = 0; j < 4; ++j)
        ou[j] = (unsigned int)f2bf(r[2*j]) | ((unsigned int)f2bf(r[2*j+1]) << 16);
    ((uint4*)y)[(size_t)row * 64 + lane] = o;
}

// ---------------- fused MFMA GEMM over all K orders ------------------------
// 3-deep LDS ring for A (global_load_lds, swizzled), counted-vmcnt pipeline:
// stage(s+2) issued in iter s; raw s_barrier (no vmem drain). B loads issued
// first each iter so the compiler's B-use wait drains exactly stage(s+1).
__global__ __launch_bounds__(256) void gemm_mfma_kernel(const unsigned short* __restrict__ T,
                                                        const unsigned short* __restrict__ WbT,
                                                        const float* __restrict__ bias,
                                                        float* __restrict__ out) {
    __shared__ unsigned short Abuf[3][128 * 64];   // 3 x 16 KB ring
    const int lane = threadIdx.x & 63;
    const int wv = threadIdx.x >> 6;
    const int v0 = blockIdx.x * 128;
    const int b = blockIdx.y;
    const int lr = lane & 15;
    const int lk = lane >> 4;

    const int lanerow = lane >> 3;
    const int cgp = (lane & 7) ^ lanerow;
    size_t goff[4];
    #pragma unroll
    for (int j = 0; j < 4; ++j) {
        int row_local = wv * 32 + j * 8 + lanerow;
        int rowg = v0 + row_local;
        if (rowg >= V_NODES) rowg = V_NODES - 1;
        goff[j] = (size_t)rowg * FDIM + b * CIN + cgp * 8;
    }

    f32x4 acc[8][2];
    #pragma unroll
    for (int mf = 0; mf < 8; ++mf)
        #pragma unroll
        for (int nf = 0; nf < 2; ++nf)
            acc[mf][nf] = (f32x4){0.f, 0.f, 0.f, 0.f};

    const unsigned short* Bb = WbT + (size_t)(wv * 32 + lr) * KTOT + lk * 8;

    // prologue: stage steps 0,1 into ring slots 0,1
    #pragma unroll
    for (int st = 0; st < 2; ++st) {
        const size_t stepoff = (size_t)(st >> 1) * ((size_t)V_NODES * FDIM) + (size_t)(st & 1) * 64;
        #pragma unroll
        for (int j = 0; j < 4; ++j)
            __builtin_amdgcn_global_load_lds(
                (const __attribute__((address_space(1))) void*)(T + goff[j] + stepoff),
                (__attribute__((address_space(3))) void*)(&Abuf[st][(wv * 32 + j * 8) * 64]),
                16, 0, 0);
    }
    asm volatile("s_waitcnt vmcnt(4)" ::: "memory");   // step 0 landed; step 1 in flight
    asm volatile("s_barrier" ::: "memory");

    int curm = 0, stm = 2;
    #pragma unroll 1
    for (int s = 0; s < 10; ++s) {
        // 1) B fragments for this step — issued FIRST (oldest in vmcnt FIFO)
        s16x8 bcur[2][2];
        #pragma unroll
        for (int c = 0; c < 2; ++c)
            #pragma unroll
            for (int nf = 0; nf < 2; ++nf)
                bcur[c][nf] = *(const s16x8*)(Bb + (size_t)nf * 16 * KTOT + s * 64 + c * 32);
        __builtin_amdgcn_sched_barrier(0);
        // 2) stage step s+2 into ring slot stm (4 global_load_lds, stay in flight)
        if (s < 8) {
            const int sn = s + 2;
            const size_t stepoff = (size_t)(sn >> 1) * ((size_t)V_NODES * FDIM) + (size_t)(sn & 1) * 64;
            #pragma unroll
            for (int j = 0; j < 4; ++j)
                __builtin_amdgcn_global_load_lds(
                    (const __attribute__((address_space(1))) void*)(T + goff[j] + stepoff),
                    (__attribute__((address_space(3))) void*)(&Abuf[stm][(wv * 32 + j * 8) * 64]),
                    16, 0, 0);
        }
        // 3) compute from ring slot curm (compiler inserts lgkmcnt for ds_reads
        //    and a vmcnt wait for bcur that also drains stage(s+1))
        const unsigned short* Ab = &Abuf[curm][0];
        #pragma unroll
        for (int c = 0; c < 2; ++c) {
            s16x8 a[8];
            #pragma unroll
            for (int mf = 0; mf < 8; ++mf) {
                int rr = mf * 16 + lr;
                int slot = ((c * 4 + lk) ^ (lr & 7)) * 8;
                a[mf] = *(const s16x8*)(Ab + rr * 64 + slot);
            }
            #pragma unroll
            for (int mf = 0; mf < 8; ++mf)
                #pragma unroll
                for (int nf = 0; nf < 2; ++nf)
                    acc[mf][nf] = __builtin_amdgcn_mfma_f32_16x16x32_bf16(a[mf], bcur[c][nf], acc[mf][nf], 0, 0, 0);
        }
        // 4) raw barrier — no vmem drain
        asm volatile("s_barrier" ::: "memory");
        curm = (curm == 2) ? 0 : curm + 1;
        stm  = (stm == 2) ? 0 : stm + 1;
    }

    // --- epilogue: transpose through LDS (reuse ring slot 0+), coalesced stores
    float* lds_f = (float*)&Abuf[0][0];            // 32 co x 132 f32
    const float bs0 = bias[wv * 32 + lr];
    const float bs1 = bias[wv * 32 + 16 + lr];
    #pragma unroll
    for (int p = 0; p < 4; ++p) {
        if (wv == p) {
            #pragma unroll
            for (int mf = 0; mf < 8; ++mf)
                #pragma unroll
                for (int nf = 0; nf < 2; ++nf) {
                    int co_l = nf * 16 + lr;
                    int vbase = mf * 16 + lk * 4;
                    f32x4 val = acc[mf][nf];
                    float bs = nf ? bs1 : bs0;
                    val[0] += bs; val[1] += bs; val[2] += bs; val[3] += bs;
                    *(f32x4*)(lds_f + co_l * 132 + vbase) = val;
                }
        }
        __syncthreads();
        #pragma unroll
        for (int i = 0; i < 4; ++i) {
            int flat = i * 256 + threadIdx.x;
            int co_l = flat >> 5;
            int v4 = flat & 31;
            int v = v0 + v4 * 4;
            if (v < V_NODES) {
                f32x4 val = *(const f32x4*)(lds_f + co_l * 132 + v4 * 4);
                *(f32x4*)(out + (size_t)(b * COUT + p * 32 + co_l) * V_NODES + v) = val;
            }
        }
        __syncthreads();
    }
}

extern "C" void kernel_launch(void* const* d_in, const int* in_sizes, int n_in,
                              void* d_out, int out_size, void* d_ws, size_t ws_size,
                              hipStream_t stream) {
    const float* x    = (const float*)d_in[0];
    const float* vals = (const float*)d_in[1];
    const float* W    = (const float*)d_in[2];
    const float* bias = (const float*)d_in[3];
    const int* rows   = (const int*)d_in[4];
    const int* cols   = (const int*)d_in[5];
    const int E = in_sizes[1];
    float* out = (float*)d_out;

    // base workspace layout
    unsigned short* T    = (unsigned short*)d_ws;
    unsigned short* WbT  = T + (size_t)KORD * V_NODES * FDIM;
    EPair* ep     = (EPair*)(WbT + (size_t)COUT * KTOT);
    int*   rowPtr = (int*)(ep + E);
    int*   cursor = rowPtr + V_NODES + 1;
    int*   cnt    = cursor + V_NODES;
    int*   blkSum = cnt + V_NODES;            // SCAN_NBLK
    // optional int8 region (aligned 16)
    char* p8 = (char*)(((uintptr_t)(blkSum + SCAN_NBLK) + 15) & ~(uintptr_t)15);
    signed char* i8A = (signed char*)p8;
    signed char* i8B = i8A + (size_t)V_NODES * FDIM;
    float* scA = (float*)(i8B + (size_t)V_NODES * FDIM);
    float* scB = scA + V_NODES;
    size_t need = (size_t)((char*)(scB + V_NODES) - (char*)d_ws);
    const bool use_i8 = (ws_size >= need);

    unsigned short* T0 = T;
    unsigned short* T1 = T + 1 * (size_t)V_NODES * FDIM;
    unsigned short* T2 = T + 2 * (size_t)V_NODES * FDIM;
    unsigned short* T3 = T + 3 * (size_t)V_NODES * FDIM;
    unsigned short* T4 = T + 4 * (size_t)V_NODES * FDIM;

    const int eBlocks = (E + 255) / 256;
    const int spB4 = (V_NODES + 3) / 4;

    // CSR build (hierarchical scan, 2 dispatches)
    hipMemsetAsync(cnt, 0, V_NODES * sizeof(int), stream);
    hist_kernel<<<eBlocks, 256, 0, stream>>>(rows, cnt, E);
    scan1_kernel<<<SCAN_NBLK, 256, 0, stream>>>(cnt, rowPtr, blkSum);
    scan23_kernel<<<SCAN_NBLK, 256, 0, stream>>>(blkSum, rowPtr, cursor);
    scatter_kernel<<<eBlocks, 256, 0, stream>>>(vals, rows, cols, cursor, ep, E);

    // T0 + weights
    dim3 tg((V_NODES + 63) / 64, FDIM / 64);
    transpose_kernel<<<tg, 256, 0, stream>>>(x, T0);
    convw_kernel<<<(KTOT * COUT + 255) / 256, 256, 0, stream>>>(W, WbT);

    if (use_i8) {
        quant_rows_kernel<<<spB4, 256, 0, stream>>>(T0, i8A, scA);
        spmm_i8_kernel<<<spB4, 256, 0, stream>>>(ep, rowPtr, i8A, scA, T0, T1, i8B, scB, 1.f, 0, 1);
        spmm_i8_kernel<<<spB4, 256, 0, stream>>>(ep, rowPtr, i8B, scB, T0, T2, i8A, scA, 2.f, 1, 1);
        spmm_i8_kernel<<<spB4, 256, 0, stream>>>(ep, rowPtr, i8A, scA, T1, T3, i8B, scB, 2.f, 1, 1);
        spmm_i8_kernel<<<spB4, 256, 0, stream>>>(ep, rowPtr, i8B, scB, T2, T4, i8A, scA, 2.f, 1, 0);
    } else {
        spmm_bf16_kernel<<<spB4, 256, 0, stream>>>(ep, rowPtr, T0, T0, T1, 1.f, 0);
        spmm_bf16_kernel<<<spB4, 256, 0, stream>>>(ep, rowPtr, T1, T0, T2, 2.f, 1);
        spmm_bf16_kernel<<<spB4, 256, 0, stream>>>(ep, rowPtr, T2, T1, T3, 2.f, 1);
        spmm_bf16_kernel<<<spB4, 256, 0, stream>>>(ep, rowPtr, T3, T2, T4, 2.f, 1);
    }

    // fused contraction over all 5 orders
    dim3 gg((V_NODES + 127) / 128, BATCH);
    gemm_mfma_kernel<<<gg, 256, 0, stream>>>(T, WbT, bias, out);
}

// Round 10
// 507.679 us; speedup vs baseline: 1.6313x; 1.1250x over previous
//
#include <hip/hip_runtime.h>

#define V_NODES 50000
#define FDIM    512   // B*Cin
#define CIN     128
#define COUT    128
#define BATCH   4
#define KORD    5
#define KTOT    (KORD * CIN)   // 640
#define SCAN_NBLK ((V_NODES + 255) / 256)   // 196

typedef short s16x8 __attribute__((ext_vector_type(8)));
typedef float f32x4 __attribute__((ext_vector_type(4)));

struct EPair { float w; int c; };   // interleaved edge: weight + col

__device__ __forceinline__ float bf2f(unsigned short u) {
    union { unsigned int i; float f; } x; x.i = ((unsigned int)u) << 16; return x.f;
}
__device__ __forceinline__ unsigned short f2bf(float f) {
    union { float f; unsigned int i; } x; x.f = f;
    unsigned int r = x.i + 0x7fffu + ((x.i >> 16) & 1u);   // RNE
    return (unsigned short)(r >> 16);
}

// ---------------- transpose: x (512, V) f32 -> T0 (V, 512) bf16 ------------
__global__ __launch_bounds__(256) void transpose_kernel(const float* __restrict__ x,
                                                        unsigned short* __restrict__ t0) {
    __shared__ float tile[64][65];
    const int v0 = blockIdx.x * 64;
    const int r0 = blockIdx.y * 64;
    const int lane = threadIdx.x & 63;
    const int w = threadIdx.x >> 6;
    #pragma unroll
    for (int i = 0; i < 16; ++i) {
        int rr = w * 16 + i;
        int v = v0 + lane;
        tile[rr][lane] = (v < V_NODES) ? x[(size_t)(r0 + rr) * V_NODES + v] : 0.0f;
    }
    __syncthreads();
    #pragma unroll
    for (int i = 0; i < 16; ++i) {
        int vv = w * 16 + i;
        int v = v0 + vv;
        if (v < V_NODES) t0[(size_t)v * FDIM + r0 + lane] = f2bf(tile[lane][vv]);
    }
}

// ---------------- W convert+transpose: W f32 [kci][co] -> WbT bf16 [co][kci]
__global__ __launch_bounds__(256) void convw_kernel(const float* __restrict__ W,
                                                    unsigned short* __restrict__ WbT) {
    int t = blockIdx.x * 256 + threadIdx.x;
    if (t >= KTOT * COUT) return;
    int kci = t >> 7, co = t & 127;
    WbT[(size_t)co * KTOT + kci] = f2bf(W[(size_t)kci * COUT + co]);
}

// ---------------- CSR build ------------------------------------------------
__global__ __launch_bounds__(256) void hist_kernel(const int* __restrict__ rows,
                                                   int* __restrict__ cnt, int E) {
    int e = blockIdx.x * 256 + threadIdx.x;
    if (e < E) atomicAdd(&cnt[rows[e]], 1);
}

__global__ __launch_bounds__(256) void scan1_kernel(const int* __restrict__ cnt,
                                                    int* __restrict__ rowPtr,
                                                    int* __restrict__ blkSum) {
    __shared__ int sh[256];
    const int t = threadIdx.x;
    const int i = blockIdx.x * 256 + t;
    int v = (i < V_NODES) ? cnt[i] : 0;
    sh[t] = v;
    __syncthreads();
    #pragma unroll
    for (int off = 1; off < 256; off <<= 1) {
        int u = (t >= off) ? sh[t - off] : 0;
        __syncthreads();
        sh[t] += u;
        __syncthreads();
    }
    if (i < V_NODES) rowPtr[i] = sh[t] - v;
    if (t == 255) blkSum[blockIdx.x] = sh[255];
}

__global__ __launch_bounds__(256) void scan23_kernel(const int* __restrict__ blkSum,
                                                     int* __restrict__ rowPtr,
                                                     int* __restrict__ cursor) {
    __shared__ int sh[256];
    const int t = threadIdx.x;
    int v = (t < SCAN_NBLK) ? blkSum[t] : 0;
    sh[t] = v;
    __syncthreads();
    #pragma unroll
    for (int off = 1; off < 256; off <<= 1) {
        int u = (t >= off) ? sh[t - off] : 0;
        __syncthreads();
        sh[t] += u;
        __syncthreads();
    }
    const int boff = sh[blockIdx.x] - blkSum[blockIdx.x];
    const int i = blockIdx.x * 256 + t;
    if (i < V_NODES) {
        int r = rowPtr[i] + boff;
        rowPtr[i] = r;
        cursor[i] = r;
    }
    if (blockIdx.x == 0 && t == 255) rowPtr[V_NODES] = sh[255];
}

__global__ __launch_bounds__(256) void scatter_kernel(const float* __restrict__ vals,
                                                      const int* __restrict__ rows,
                                                      const int* __restrict__ cols,
                                                      int* __restrict__ cursor,
                                                      EPair* __restrict__ ep, int E) {
    int e = blockIdx.x * 256 + threadIdx.x;
    if (e >= E) return;
    int r = rows[e];
    int pos = atomicAdd(&cursor[r], 1);
    EPair p; p.w = vals[e]; p.c = cols[e];
    ep[pos] = p;
}

// ---------------- quantize bf16 rows -> int8 + per-row scale ---------------
__global__ __launch_bounds__(256) void quant_rows_kernel(const unsigned short* __restrict__ xb,
                                                         signed char* __restrict__ xi,
                                                         float* __restrict__ xs) {
    const int wid = threadIdx.x >> 6;
    const int lane = threadIdx.x & 63;
    const int row = blockIdx.x * 4 + wid;
    if (row >= V_NODES) return;
    uint4 q = ((const uint4*)xb)[(size_t)row * 64 + lane];
    unsigned int u[4] = {q.x, q.y, q.z, q.w};
    float f[8];
    #pragma unroll
    for (int j = 0; j < 4; ++j) {
        f[2*j+0] = bf2f((unsigned short)(u[j] & 0xffffu));
        f[2*j+1] = bf2f((unsigned short)(u[j] >> 16));
    }
    float m = 0.f;
    #pragma unroll
    for (int j = 0; j < 8; ++j) m = fmaxf(m, fabsf(f[j]));
    #pragma unroll
    for (int off = 1; off < 64; off <<= 1) m = fmaxf(m, __shfl_xor(m, off, 64));
    float inv = (m > 0.f) ? 127.f / m : 0.f;
    uint2 o; unsigned int ow[2] = {0u, 0u};
    #pragma unroll
    for (int j = 0; j < 8; ++j) {
        int si = (int)rintf(f[j] * inv);
        si = max(-127, min(127, si));
        ow[j >> 2] |= ((unsigned int)(si & 0xff)) << (8 * (j & 3));
    }
    o.x = ow[0]; o.y = ow[1];
    ((uint2*)xi)[(size_t)row * 64 + lane] = o;
    if (lane == 0) xs[row] = m / 127.f;
}

// ---------------- CSR SpMM: i8 in, i8 out -----------------------------------
// y = alpha * sum(w * xsc[c] * xi8[c]) - beta * oldsc[row]*oldi8[row]
__global__ __launch_bounds__(256) void spmm_i8_kernel(const EPair* __restrict__ ep,
                                                      const int* __restrict__ rowPtr,
                                                      const signed char* __restrict__ xi,
                                                      const float* __restrict__ xsc,
                                                      const signed char* __restrict__ oldi,
                                                      const float* __restrict__ oldsc,
                                                      signed char* __restrict__ yi,
                                                      float* __restrict__ ysc,
                                                      float alpha, int beta) {
    const int wid = threadIdx.x >> 6;
    const int lane = threadIdx.x & 63;
    const int row = blockIdx.x * 4 + wid;
    if (row >= V_NODES) return;
    const int s = rowPtr[row], e_end = rowPtr[row + 1];
    const uint2* __restrict__ xq = (const uint2*)xi;   // 64 x 8B per row

    float acc[8];
    #pragma unroll
    for (int j = 0; j < 8; ++j) acc[j] = 0.f;

    int e = s;
    for (; e + 3 < e_end; e += 4) {
        EPair p[4];
        #pragma unroll
        for (int i = 0; i < 4; ++i) p[i] = ep[e + i];
        float w[4];
        #pragma unroll
        for (int i = 0; i < 4; ++i) w[i] = p[i].w * xsc[p[i].c];
        uint2 q[4];
        #pragma unroll
        for (int i = 0; i < 4; ++i) q[i] = xq[(size_t)p[i].c * 64 + lane];
        #pragma unroll
        for (int i = 0; i < 4; ++i) {
            #pragma unroll
            for (int wd = 0; wd < 2; ++wd) {
                unsigned int uu = wd ? q[i].y : q[i].x;
                #pragma unroll
                for (int b = 0; b < 4; ++b) {
                    float xv = (float)((signed char)(uu >> (8 * b)));
                    acc[wd * 4 + b] += w[i] * xv;
                }
            }
        }
    }
    for (; e < e_end; ++e) {
        EPair p0 = ep[e];
        float w0 = p0.w * xsc[p0.c];
        uint2 q0 = xq[(size_t)p0.c * 64 + lane];
        #pragma unroll
        for (int wd = 0; wd < 2; ++wd) {
            unsigned int uu = wd ? q0.y : q0.x;
            #pragma unroll
            for (int b = 0; b < 4; ++b) {
                float xv = (float)((signed char)(uu >> (8 * b)));
                acc[wd * 4 + b] += w0 * xv;
            }
        }
    }

    float r[8];
    #pragma unroll
    for (int j = 0; j < 8; ++j) r[j] = alpha * acc[j];
    if (beta) {
        uint2 q = ((const uint2*)oldi)[(size_t)row * 64 + lane];
        const float os = oldsc[row];
        #pragma unroll
        for (int wd = 0; wd < 2; ++wd) {
            unsigned int uu = wd ? q.y : q.x;
            #pragma unroll
            for (int b = 0; b < 4; ++b)
                r[wd * 4 + b] -= os * (float)((signed char)(uu >> (8 * b)));
        }
    }

    // quantize result -> i8 + per-row scale
    float m = 0.f;
    #pragma unroll
    for (int j = 0; j < 8; ++j) m = fmaxf(m, fabsf(r[j]));
    #pragma unroll
    for (int off = 1; off < 64; off <<= 1) m = fmaxf(m, __shfl_xor(m, off, 64));
    float inv = (m > 0.f) ? 127.f / m : 0.f;
    unsigned int ow[2] = {0u, 0u};
    #pragma unroll
    for (int j = 0; j < 8; ++j) {
        int si = (int)rintf(r[j] * inv);
        si = max(-127, min(127, si));
        ow[j >> 2] |= ((unsigned int)(si & 0xff)) << (8 * (j & 3));
    }
    uint2 oi; oi.x = ow[0]; oi.y = ow[1];
    ((uint2*)yi)[(size_t)row * 64 + lane] = oi;
    if (lane == 0) ysc[row] = m / 127.f;
}

// dequant 8 i8 (uint2) by scale s -> bf16x8 (exact int->bf16, RNE after scale)
__device__ __forceinline__ s16x8 dq8(uint2 q, float s) {
    float f0 = s * (float)((signed char)(q.x));
    float f1 = s * (float)((signed char)(q.x >> 8));
    float f2 = s * (float)((signed char)(q.x >> 16));
    float f3 = s * (float)((signed char)(q.x >> 24));
    float f4 = s * (float)((signed char)(q.y));
    float f5 = s * (float)((signed char)(q.y >> 8));
    float f6 = s * (float)((signed char)(q.y >> 16));
    float f7 = s * (float)((signed char)(q.y >> 24));
    unsigned int d0, d1, d2, d3;
    asm("v_cvt_pk_bf16_f32 %0, %1, %2" : "=v"(d0) : "v"(f0), "v"(f1));
    asm("v_cvt_pk_bf16_f32 %0, %1, %2" : "=v"(d1) : "v"(f2), "v"(f3));
    asm("v_cvt_pk_bf16_f32 %0, %1, %2" : "=v"(d2) : "v"(f4), "v"(f5));
    asm("v_cvt_pk_bf16_f32 %0, %1, %2" : "=v"(d3) : "v"(f6), "v"(f7));
    union { unsigned int u[4]; s16x8 v; } r;
    r.u[0] = d0; r.u[1] = d1; r.u[2] = d2; r.u[3] = d3;
    return r.v;
}

// ---------------- fused MFMA GEMM over all K orders (i8 A) ------------------
// A staged from i8 T (8 KB/step, 3-deep ring, counted pipeline, raw barriers),
// dequantized to bf16 in registers with per-row per-order scale. B bf16 direct.
__global__ __launch_bounds__(256) void gemm_mfma_kernel(const signed char* __restrict__ Ti8,
                                                        const float* __restrict__ Tsc,
                                                        const unsigned short* __restrict__ WbT,
                                                        const float* __restrict__ bias,
                                                        float* __restrict__ out) {
    __shared__ signed char Abuf[3][128 * 64];   // 3 x 8 KB ring
    const int lane = threadIdx.x & 63;
    const int wv = threadIdx.x >> 6;
    const int v0 = blockIdx.x * 128;
    const int b = blockIdx.y;
    const int lr = lane & 15;
    const int lk = lane >> 4;

    // staging: 2 loads/thread/step. flat = j*256+tid -> row_local=flat>>2, chunk=flat&3
    // source chunk pre-swizzled: chunk' = chunk ^ (row_local&3); LDS dest linear.
    size_t gofB[2];
    #pragma unroll
    for (int j = 0; j < 2; ++j) {
        int flat = j * 256 + (int)threadIdx.x;
        int rl = flat >> 2;
        int ch = flat & 3;
        int rowg = v0 + rl;
        if (rowg >= V_NODES) rowg = V_NODES - 1;
        gofB[j] = (size_t)rowg * FDIM + b * CIN + (size_t)((ch ^ (rl & 3)) << 4);
    }

    f32x4 acc[8][2];
    #pragma unroll
    for (int mf = 0; mf < 8; ++mf)
        #pragma unroll
        for (int nf = 0; nf < 2; ++nf)
            acc[mf][nf] = (f32x4){0.f, 0.f, 0.f, 0.f};

    const unsigned short* Bb = WbT + (size_t)(wv * 32 + lr) * KTOT + lk * 8;

    // prologue: stage steps 0,1 into slots 0,1
    #pragma unroll
    for (int st = 0; st < 2; ++st) {
        const size_t soff = (size_t)(st >> 1) * ((size_t)V_NODES * FDIM) + (size_t)((st & 1) * 64);
        #pragma unroll
        for (int j = 0; j < 2; ++j)
            __builtin_amdgcn_global_load_lds(
                (const __attribute__((address_space(1))) void*)(Ti8 + gofB[j] + soff),
                (__attribute__((address_space(3))) void*)(&Abuf[st][(j * 256 + wv * 64) * 16]),
                16, 0, 0);
    }
    asm volatile("s_waitcnt vmcnt(2)" ::: "memory");   // step 0 landed; step 1 in flight
    asm volatile("s_barrier" ::: "memory");

    // per-order row scales (order 0)
    float smf[8];
    #pragma unroll
    for (int mf = 0; mf < 8; ++mf) {
        int vv = v0 + mf * 16 + lr;
        if (vv >= V_NODES) vv = V_NODES - 1;
        smf[mf] = Tsc[vv];
    }

    int curm = 0, stm = 2;
    #pragma unroll 1
    for (int s = 0; s < 10; ++s) {
        // 1) B fragments + (on order change) scale reloads — issued FIRST (oldest in FIFO)
        s16x8 bcur[2][2];
        #pragma unroll
        for (int c = 0; c < 2; ++c)
            #pragma unroll
            for (int nf = 0; nf < 2; ++nf)
                bcur[c][nf] = *(const s16x8*)(Bb + (size_t)nf * 16 * KTOT + s * 64 + c * 32);
        if (s > 0 && (s & 1) == 0) {
            const int ord = s >> 1;
            #pragma unroll
            for (int mf = 0; mf < 8; ++mf) {
                int vv = v0 + mf * 16 + lr;
                if (vv >= V_NODES) vv = V_NODES - 1;
                smf[mf] = Tsc[(size_t)ord * V_NODES + vv];
            }
        }
        __builtin_amdgcn_sched_barrier(0);
        // 2) stage step s+2 (stays in flight across the compute + barrier)
        if (s < 8) {
            const int sn = s + 2;
            const size_t soff = (size_t)(sn >> 1) * ((size_t)V_NODES * FDIM) + (size_t)((sn & 1) * 64);
            #pragma unroll
            for (int j = 0; j < 2; ++j)
                __builtin_amdgcn_global_load_lds(
                    (const __attribute__((address_space(1))) void*)(Ti8 + gofB[j] + soff),
                    (__attribute__((address_space(3))) void*)(&Abuf[stm][(j * 256 + wv * 64) * 16]),
                    16, 0, 0);
        }
        // 3) compute from slot curm: ds_read_b64 -> dequant -> MFMA
        const signed char* Ab = &Abuf[curm][0];
        #pragma unroll
        for (int c = 0; c < 2; ++c) {
            s16x8 a[8];
            #pragma unroll
            for (int mf = 0; mf < 8; ++mf) {
                int row = mf * 16 + lr;
                int L = c * 32 + lk * 8;
                int phys = row * 64 + ((((L >> 4) ^ (row & 3)) << 4) | (L & 15));
                uint2 q = *(const uint2*)(Ab + phys);
                a[mf] = dq8(q, smf[mf]);
            }
            #pragma unroll
            for (int mf = 0; mf < 8; ++mf)
                #pragma unroll
                for (int nf = 0; nf < 2; ++nf)
                    acc[mf][nf] = __builtin_amdgcn_mfma_f32_16x16x32_bf16(a[mf], bcur[c][nf], acc[mf][nf], 0, 0, 0);
        }
        // 4) raw barrier — no vmem drain
        asm volatile("s_barrier" ::: "memory");
        curm = (curm == 2) ? 0 : curm + 1;
        stm  = (stm == 2) ? 0 : stm + 1;
    }

    // --- epilogue: transpose through LDS (reuse ring), coalesced f32x4 stores
    float* lds_f = (float*)&Abuf[0][0];            // 32 co x 132 f32 = 16.9 KB < 24 KB
    const float bs0 = bias[wv * 32 + lr];
    const float bs1 = bias[wv * 32 + 16 + lr];
    #pragma unroll
    for (int p = 0; p < 4; ++p) {
        if (wv == p) {
            #pragma unroll
            for (int mf = 0; mf < 8; ++mf)
                #pragma unroll
                for (int nf = 0; nf < 2; ++nf) {
                    int co_l = nf * 16 + lr;
                    int vbase = mf * 16 + lk * 4;
                    f32x4 val = acc[mf][nf];
                    float bs = nf ? bs1 : bs0;
                    val[0] += bs; val[1] += bs; val[2] += bs; val[3] += bs;
                    *(f32x4*)(lds_f + co_l * 132 + vbase) = val;
                }
        }
        __syncthreads();
        #pragma unroll
        for (int i = 0; i < 4; ++i) {
            int flat = i * 256 + threadIdx.x;
            int co_l = flat >> 5;
            int v4 = flat & 31;
            int v = v0 + v4 * 4;
            if (v < V_NODES) {
                f32x4 val = *(const f32x4*)(lds_f + co_l * 132 + v4 * 4);
                *(f32x4*)(out + (size_t)(b * COUT + p * 32 + co_l) * V_NODES + v) = val;
            }
        }
        __syncthreads();
    }
}

extern "C" void kernel_launch(void* const* d_in, const int* in_sizes, int n_in,
                              void* d_out, int out_size, void* d_ws, size_t ws_size,
                              hipStream_t stream) {
    const float* x    = (const float*)d_in[0];
    const float* vals = (const float*)d_in[1];
    const float* W    = (const float*)d_in[2];
    const float* bias = (const float*)d_in[3];
    const int* rows   = (const int*)d_in[4];
    const int* cols   = (const int*)d_in[5];
    const int E = in_sizes[1];
    float* out = (float*)d_out;

    // workspace: bf16 T0 (transpose scratch), i8 T0..T4 + scales, WbT, edges, CSR
    unsigned short* T0bf = (unsigned short*)d_ws;                  // V*512 bf16
    signed char* i8T = (signed char*)(T0bf + (size_t)V_NODES * FDIM);  // 5 * V*512
    float* sc  = (float*)(i8T + (size_t)KORD * V_NODES * FDIM);    // 5 * V
    unsigned short* WbT = (unsigned short*)(sc + (size_t)KORD * V_NODES);
    EPair* ep     = (EPair*)(WbT + (size_t)COUT * KTOT);
    int*   rowPtr = (int*)(ep + E);
    int*   cursor = rowPtr + V_NODES + 1;
    int*   cnt    = cursor + V_NODES;
    int*   blkSum = cnt + V_NODES;            // SCAN_NBLK

    signed char* i8T0 = i8T;
    signed char* i8T1 = i8T + 1 * (size_t)V_NODES * FDIM;
    signed char* i8T2 = i8T + 2 * (size_t)V_NODES * FDIM;
    signed char* i8T3 = i8T + 3 * (size_t)V_NODES * FDIM;
    signed char* i8T4 = i8T + 4 * (size_t)V_NODES * FDIM;
    float* sc0 = sc + 0 * (size_t)V_NODES;
    float* sc1 = sc + 1 * (size_t)V_NODES;
    float* sc2 = sc + 2 * (size_t)V_NODES;
    float* sc3 = sc + 3 * (size_t)V_NODES;
    float* sc4 = sc + 4 * (size_t)V_NODES;

    const int eBlocks = (E + 255) / 256;
    const int spB4 = (V_NODES + 3) / 4;

    // CSR build
    hipMemsetAsync(cnt, 0, V_NODES * sizeof(int), stream);
    hist_kernel<<<eBlocks, 256, 0, stream>>>(rows, cnt, E);
    scan1_kernel<<<SCAN_NBLK, 256, 0, stream>>>(cnt, rowPtr, blkSum);
    scan23_kernel<<<SCAN_NBLK, 256, 0, stream>>>(blkSum, rowPtr, cursor);
    scatter_kernel<<<eBlocks, 256, 0, stream>>>(vals, rows, cols, cursor, ep, E);

    // T0 + weights
    dim3 tg((V_NODES + 63) / 64, FDIM / 64);
    transpose_kernel<<<tg, 256, 0, stream>>>(x, T0bf);
    convw_kernel<<<(KTOT * COUT + 255) / 256, 256, 0, stream>>>(W, WbT);
    quant_rows_kernel<<<spB4, 256, 0, stream>>>(T0bf, i8T0, sc0);

    // Chebyshev recurrence — all state in i8 + per-row scale
    spmm_i8_kernel<<<spB4, 256, 0, stream>>>(ep, rowPtr, i8T0, sc0, i8T0, sc0, i8T1, sc1, 1.f, 0);
    spmm_i8_kernel<<<spB4, 256, 0, stream>>>(ep, rowPtr, i8T1, sc1, i8T0, sc0, i8T2, sc2, 2.f, 1);
    spmm_i8_kernel<<<spB4, 256, 0, stream>>>(ep, rowPtr, i8T2, sc2, i8T1, sc1, i8T3, sc3, 2.f, 1);
    spmm_i8_kernel<<<spB4, 256, 0, stream>>>(ep, rowPtr, i8T3, sc3, i8T2, sc2, i8T4, sc4, 2.f, 1);

    // fused contraction over all 5 orders (A from i8 + scales)
    dim3 gg((V_NODES + 127) / 128, BATCH);
    gemm_mfma_kernel<<<gg, 256, 0, stream>>>(i8T, sc, WbT, bias, out);
}